// Round 7
// baseline (3923.666 us; speedup 1.0000x reference)
//
#include <hip/hip_runtime.h>
#include <hip/hip_bf16.h>

typedef unsigned short u16;
using bf16x8 = __attribute__((ext_vector_type(8))) short;
using f32x4  = __attribute__((ext_vector_type(4))) float;

#define NB   4
#define NT   90
#define NIMG 360
#define LL   240
#define DD   64
#define HID  512
#define NJ   2048
#define PBLK 128   // persistent scan blocks

#define DEV __device__ __forceinline__

DEV float bf2f(u16 x){ unsigned int u = ((unsigned int)x) << 16; float f; __builtin_memcpy(&f, &u, 4); return f; }
DEV u16 f2bf(float f){ unsigned int u; __builtin_memcpy(&u, &f, 4); unsigned int r = (u + 0x7FFFu + ((u >> 16) & 1u)) >> 16; return (u16)r; }
DEV float sigm(float x){ return 1.f / (1.f + __expf(-x)); }
DEV float tanh_f(float x){ x = fminf(fmaxf(x, -15.f), 15.f); float e = __expf(2.f*x); return (e - 1.f) / (e + 1.f); }

// L3-coherent (agent-scope, relaxed) accessors for cross-XCD mutable state.
DEV void  ast(float* p, float v){ __hip_atomic_store(p, v, __ATOMIC_RELAXED, __HIP_MEMORY_SCOPE_AGENT); }
DEV float ald(const float* p){ return __hip_atomic_load(p, __ATOMIC_RELAXED, __HIP_MEMORY_SCOPE_AGENT); }
DEV void  astu(unsigned int* p, unsigned int v){ __hip_atomic_store(p, v, __ATOMIC_RELAXED, __HIP_MEMORY_SCOPE_AGENT); }
DEV unsigned int aldu(const unsigned int* p){ return __hip_atomic_load(p, __ATOMIC_RELAXED, __HIP_MEMORY_SCOPE_AGENT); }

// ---------------- workspace layout (bytes) ----------------
static const size_t G_OFF     = 0;            // u16 [90][240][128][64]  = 353,894,400 B (span-major layout)
static const size_t CAMCL_OFF = 0;            // conv temporaries alias over G (dead before G written)
static const size_t A1_OFF    = 88473600;
static const size_t A2_OFF    = 154828800;
static const size_t A3_OFF    = 182476800;
static const size_t A4_OFF    = 190771200;
static const size_t A5_OFF    = 201830400;
static const size_t W1B_OFF   = 212889600;
static const size_t W2B_OFF   = 212903936;
static const size_t W3B_OFF   = 212968448;
static const size_t W4B_OFF   = 213075968;
static const size_t W5B_OFF   = 213137408;
static const size_t FEATS_OFF = 353894400;    // fp32 [360][240][64]; dead during scan -> scan state aliases here
static const size_t SC_GATES  = 353894400;    // fp32 [2][4][2048] = 64KB (double-buffered)
static const size_t SC_FLAGS  = 353959936;    // u32 [128][32] = 16KB (128B-spaced arrival flags)
static const size_t SC_GO     = 353976320;    // u32 go word (128B slot)
static const size_t PROJ_OFF  = 376012800;    // fp32 [360][240][64]
static const size_t WWT_OFF   = 398131200;    // fp32 [512][64]   w_w^T
static const size_t WHHP_OFF  = 398262272;    // bf16 [512][2048] whh^T, j-permuted
static const size_t BSUM_OFF  = 400359424;    // fp32 [2048] bih+bhh, j-permuted
static const size_t SW1T_OFF  = 400367616;    // fp32 [512][100]
static const size_t VW1T_OFF  = 400572416;    // fp32 [512][100]
static const size_t HSEQ_OFF  = 400809984;    // fp32 [90][4][512]
static const size_t WS_NEEDED = 401547264;

// ---------------- camera NCHW fp32 -> channels-last bf16 [n][h][w][8] ----------------
__global__ __launch_bounds__(256) void cam_to_cl(const float* __restrict__ cam, u16* __restrict__ out)
{
    int i = blockIdx.x * 256 + threadIdx.x;
    if (i >= NIMG * 96 * 160) return;
    int hw = i % (96 * 160);
    int n  = i / (96 * 160);
    const float* p = cam + (size_t)n * 3 * 96 * 160 + hw;
    bf16x8 v;
    v[0] = (short)f2bf(p[0]);
    v[1] = (short)f2bf(p[15360]);
    v[2] = (short)f2bf(p[30720]);
    v[3] = 0; v[4] = 0; v[5] = 0; v[6] = 0; v[7] = 0;
    *(bf16x8*)&out[(size_t)i * 8] = v;
}

// ---------------- weight prep for convs ----------------
__global__ __launch_bounds__(256) void prep_wbf(
    const float* __restrict__ w, u16* __restrict__ wbf,
    int COUT, int CIN, int CI_PAD, int KHW, int CELLS_PAD, int M_PAD)
{
    int K_PAD = CELLS_PAD * CI_PAD;
    int total = M_PAD * K_PAD;
    for (int i = blockIdx.x * 256 + threadIdx.x; i < total; i += gridDim.x * 256){
        int co = i / K_PAD, kk = i % K_PAD;
        int cell = kk / CI_PAD, ci = kk % CI_PAD;
        float v = 0.f;
        if (co < COUT && cell < KHW * KHW && ci < CIN){
            int kh = cell / KHW, kw = cell % KHW;
            v = w[((size_t)(co * CIN + ci) * KHW + kh) * KHW + kw];
        }
        wbf[i] = f2bf(v);
    }
}

// ---------------- implicit-GEMM MFMA conv (channels-last bf16 in/out) ----------------
template<int CI_PAD, int M_PAD, int COUT, int CO_STORE, int KHW, int CELLS_PAD,
         int S, int P, int HIN, int WIN, int HOUT, int WOUT, int TOH, int TOW>
__global__ __launch_bounds__(256) void conv_mfma(
    const u16* __restrict__ in, const u16* __restrict__ wbf,
    const float* __restrict__ bias, u16* __restrict__ out)
{
    constexpr int K_PAD = CELLS_PAD * CI_PAD;
    constexpr int CP8   = CI_PAD / 8;
    constexpr int TIH   = (TOH - 1) * S + KHW;
    constexpr int TIW   = (TOW - 1) * S + KHW;
    constexpr int TIW_H = (TIW + 1) / 2;
    constexpr int NF    = TOH * TOW / 16;
    constexpr int NK0   = K_PAD / 32;
    constexpr int MF    = M_PAD / 16;
    constexpr int NPW   = (NF + 3) / 4;
    constexpr int LDSE  = (S == 2) ? TIH * CP8 * 2 * TIW_H * 8 : TIH * CP8 * TIW * 8;
    static_assert((TOH * TOW) % 16 == 0, "N tile");
    static_assert(K_PAD % 32 == 0, "K pad");

    __shared__ u16 lds[LDSE];

    int tile = blockIdx.x, n = blockIdx.y;
    constexpr int TW_T = WOUT / TOW;
    int th = tile / TW_T, tw = tile % TW_T;
    int oh0 = th * TOH, ow0 = tw * TOW;
    int ih0 = oh0 * S - P, iw0 = ow0 * S - P;
    int tid = threadIdx.x;

    constexpr int CHUNKS = TIH * TIW * CP8;
    for (int i = tid; i < CHUNKS; i += 256){
        int c8 = i % CP8; int r2 = i / CP8;
        int iw = r2 % TIW, ih = r2 / TIW;
        int ihg = ih0 + ih, iwg = iw0 + iw;
        bf16x8 v = {0,0,0,0,0,0,0,0};
        if (ihg >= 0 && ihg < HIN && iwg >= 0 && iwg < WIN)
            v = *(const bf16x8*)&in[(((size_t)n * HIN + ihg) * WIN + iwg) * CI_PAD + c8 * 8];
        int off;
        if (S == 2) off = (((ih * CP8 + c8) * 2 + (iw & 1)) * TIW_H + (iw >> 1)) * 8;
        else        off = ((ih * CP8 + c8) * TIW + iw) * 8;
        *(bf16x8*)&lds[off] = v;
    }
    __syncthreads();

    int lane = tid & 63, wv = tid >> 6;
    int col = lane & 15, grp = lane >> 4;

    int ihb[NPW], iwb[NPW];
    bool act[NPW];
#pragma unroll
    for (int i2 = 0; i2 < NPW; i2++){
        int nf = wv + i2 * 4;
        act[i2] = (nf < NF);
        int nfc = act[i2] ? nf : 0;
        int nsp = nfc * 16 + col;
        ihb[i2] = (nsp / TOW) * S;
        iwb[i2] = (nsp % TOW) * S;
    }

    f32x4 acc[MF][NPW];
#pragma unroll
    for (int mf = 0; mf < MF; mf++)
#pragma unroll
        for (int i2 = 0; i2 < NPW; i2++)
            acc[mf][i2] = (f32x4){0.f, 0.f, 0.f, 0.f};

    for (int k0 = 0; k0 < NK0; k0++){
        bf16x8 a[MF];
#pragma unroll
        for (int mf = 0; mf < MF; mf++)
            a[mf] = *(const bf16x8*)&wbf[(size_t)(mf * 16 + col) * K_PAD + k0 * 32 + grp * 8];
        int k8 = k0 * 32 + grp * 8;
        int cell = k8 / CI_PAD;
        int ci0  = k8 - cell * CI_PAD;
        if (cell >= KHW * KHW) cell = 0;
        int kh = cell / KHW, kw = cell - (cell / KHW) * KHW;
        int cb = ci0 >> 3;
#pragma unroll
        for (int i2 = 0; i2 < NPW; i2++){
            if (!act[i2]) continue;
            int ih = ihb[i2] + kh;
            int off;
            if (S == 2) off = (((ih * CP8 + cb) * 2 + (kw & 1)) * TIW_H + (iwb[i2] >> 1) + (kw >> 1)) * 8;
            else        off = ((ih * CP8 + cb) * TIW + iwb[i2] + kw) * 8;
            bf16x8 b = *(const bf16x8*)&lds[off];
#pragma unroll
            for (int mf = 0; mf < MF; mf++)
                acc[mf][i2] = __builtin_amdgcn_mfma_f32_16x16x32_bf16(a[mf], b, acc[mf][i2], 0, 0, 0);
        }
    }

#pragma unroll
    for (int i2 = 0; i2 < NPW; i2++){
        if (!act[i2]) continue;
        int nf = wv + i2 * 4;
        int nsp = nf * 16 + col;
        int oh = oh0 + nsp / TOW, ow = ow0 + nsp % TOW;
        size_t obase = (((size_t)n * HOUT + oh) * WOUT + ow) * CO_STORE;
#pragma unroll
        for (int mf = 0; mf < MF; mf++){
            int cobase = mf * 16 + grp * 4;
#pragma unroll
            for (int r = 0; r < 4; r++){
                int co = cobase + r;
                if (co < CO_STORE){
                    float x = (co < COUT) ? fmaxf(acc[mf][i2][r] + bias[co], 0.f) : 0.f;
                    out[obase + co] = f2bf(x);
                }
            }
        }
    }
}

// ---------------- feats rearrange ----------------
__global__ __launch_bounds__(256) void extract_feats(const u16* __restrict__ a5, float* __restrict__ feats)
{
    int idx = blockIdx.x * 256 + threadIdx.x;
    if (idx >= NIMG * 12 * 20 * 64) return;
    int c = idx & 63; int t1 = idx >> 6;
    int w = t1 % 20; t1 /= 20;
    int h = t1 % 12; int n = t1 / 12;
    float v = bf2f(a5[idx]);
    int flat = w * 768 + c * 12 + h;
    int d = flat / 240, l = flat % 240;
    feats[((size_t)n * LL + l) * DD + d] = v;
}

// ---------------- proj = feats @ proj_w.T + proj_b ----------------
__global__ __launch_bounds__(256) void proj_kernel(
    const float* __restrict__ feats, const float* __restrict__ pw,
    const float* __restrict__ pb, float* __restrict__ proj)
{
    __shared__ float pws[64][65];
    __shared__ float fs[4][64];
    int tid = threadIdx.x;
    size_t R0 = (size_t)blockIdx.x * 4;
    for (int i = tid; i < 4096; i += 256){
        int dd = i / 64, d = i % 64;
        pws[d][dd] = pw[dd*64 + d];
    }
    { int r = tid / 64, d = tid % 64; fs[r][d] = feats[(R0 + r)*64 + d]; }
    __syncthreads();
    int r = tid / 64, dd = tid % 64;
    float a = pb[dd];
    for (int d = 0; d < 64; d++) a = fmaf(fs[r][d], pws[d][dd], a);
    proj[(R0 + r)*64 + dd] = a;
}

// ---------------- prep: whh permute, bias combine, w_w transpose ----------------
__global__ __launch_bounds__(256) void prep(
    const float* __restrict__ w_w, const float* __restrict__ whh,
    const float* __restrict__ bih, const float* __restrict__ bhh,
    float* __restrict__ w_wT, u16* __restrict__ whh_p, float* __restrict__ bsum)
{
    int idx = blockIdx.x * 256 + threadIdx.x;
    int stride = gridDim.x * 256;
    for (int i = idx; i < 512*64; i += stride){
        int k = i / 64, dd = i % 64;
        w_wT[i] = w_w[dd*512 + k];
    }
    for (int i = idx; i < 512*2048; i += stride){
        int k = i / 2048, jj = i % 2048;
        int u = jj >> 2, g = jj & 3, j = g*512 + u;
        whh_p[i] = f2bf(whh[(size_t)j*512 + k]);
    }
    for (int i = idx; i < 2048; i += stride){
        int u = i >> 2, g = i & 3, j = g*512 + u;
        bsum[i] = bih[j] + bhh[j];
    }
}

// ---------------- prep2: MLP first-layer transposes ----------------
__global__ __launch_bounds__(256) void prep2(
    const float* __restrict__ sw1, const float* __restrict__ vw1,
    float* __restrict__ sw1T, float* __restrict__ vw1T)
{
    int idx = blockIdx.x * 256 + threadIdx.x;
    int stride = gridDim.x * 256;
    for (int i = idx; i < 512*100; i += stride){
        int k = i / 100, u = i % 100;
        sw1T[i] = sw1[u*512 + k];
        vw1T[i] = vw1[u*512 + k];
    }
}

// ---------------- gcompute via MFMA: B staged once, 3 m-tiles looped inside ----------------
// G layout (span-major): G[((t*240 + l)*128 + s)*64 + b*16 + jjl], jj = s*16 + jjl.
__global__ __launch_bounds__(256, 2) void gcompute_mfma2(
    const float* __restrict__ feats, const float* __restrict__ wih, u16* __restrict__ G)
{
    __shared__ u16 Bsw[256 * 64];
    __shared__ u16 Asw[128 * 64];
    float (*obuf)[1024] = (float(*)[1024])Asw;

    int jt = blockIdx.x, l = blockIdx.y;
    int j0 = jt * 256;
    int tid = threadIdx.x;
    int g8 = tid & 7;

    for (int p = 0; p < 8; p++){
        int row = p * 32 + (tid >> 3);
        int jj = j0 + row;
        int j = (jj & 3) * 512 + (jj >> 2);
        const float* src = wih + (size_t)j * 15360 + l * 64 + g8 * 8;
        float4 v0 = *(const float4*)src;
        float4 v1 = *(const float4*)(src + 4);
        bf16x8 pk;
        pk[0]=(short)f2bf(v0.x); pk[1]=(short)f2bf(v0.y); pk[2]=(short)f2bf(v0.z); pk[3]=(short)f2bf(v0.w);
        pk[4]=(short)f2bf(v1.x); pk[5]=(short)f2bf(v1.y); pk[6]=(short)f2bf(v1.z); pk[7]=(short)f2bf(v1.w);
        *(bf16x8*)&Bsw[(row * 8 + (g8 ^ (row & 7))) * 8] = pk;
    }
    __syncthreads();

    int lane = tid & 63, w = tid >> 6;
    int col = lane & 15, grp = lane >> 4;

    bf16x8 bfr[2][4];
#pragma unroll
    for (int k0 = 0; k0 < 2; k0++)
#pragma unroll
        for (int nf = 0; nf < 4; nf++){
            int row = w * 64 + nf * 16 + col;
            bfr[k0][nf] = *(const bf16x8*)&Bsw[(row * 8 + ((k0 * 4 + grp) ^ (row & 7))) * 8];
        }

    for (int mt = 0; mt < 3; mt++){
        int m0 = mt * 128;
        __syncthreads();
        for (int p = 0; p < 4; p++){
            int row = p * 32 + (tid >> 3);
            const float* src = feats + ((size_t)(m0 + row) * LL + l) * DD + g8 * 8;
            float4 v0 = *(const float4*)src;
            float4 v1 = *(const float4*)(src + 4);
            bf16x8 pk;
            pk[0]=(short)f2bf(v0.x); pk[1]=(short)f2bf(v0.y); pk[2]=(short)f2bf(v0.z); pk[3]=(short)f2bf(v0.w);
            pk[4]=(short)f2bf(v1.x); pk[5]=(short)f2bf(v1.y); pk[6]=(short)f2bf(v1.z); pk[7]=(short)f2bf(v1.w);
            *(bf16x8*)&Asw[(row * 8 + (g8 ^ (row & 7))) * 8] = pk;
        }
        __syncthreads();

        f32x4 acc[8][4];
#pragma unroll
        for (int mf = 0; mf < 8; mf++)
#pragma unroll
            for (int nf = 0; nf < 4; nf++) acc[mf][nf] = (f32x4){0.f,0.f,0.f,0.f};

#pragma unroll
        for (int k0 = 0; k0 < 2; k0++){
#pragma unroll
            for (int mf = 0; mf < 8; mf++){
                int row = mf * 16 + col;
                bf16x8 a = *(const bf16x8*)&Asw[(row * 8 + ((k0 * 4 + grp) ^ (row & 7))) * 8];
#pragma unroll
                for (int nf = 0; nf < 4; nf++)
                    acc[mf][nf] = __builtin_amdgcn_mfma_f32_16x16x32_bf16(a, bfr[k0][nf], acc[mf][nf], 0, 0, 0);
            }
        }
        __syncthreads();

#pragma unroll
        for (int mf = 0; mf < 8; mf++){
#pragma unroll
            for (int nf = 0; nf < 4; nf++)
#pragma unroll
                for (int r = 0; r < 4; r++)
                    obuf[w][(grp * 4 + r) * 64 + nf * 16 + col] = acc[mf][nf][r];
#pragma unroll
            for (int p = 0; p < 2; p++){
                int rloc = p * 8 + (lane >> 3);
                int c0 = (lane & 7) * 8;
                float4 r0 = *(const float4*)&obuf[w][rloc * 64 + c0];
                float4 r1 = *(const float4*)&obuf[w][rloc * 64 + c0 + 4];
                int m = m0 + mf * 16 + rloc;
                if (m < NIMG){
                    int b = m / NT, tt = m % NT;
                    int jj8 = j0 + w * 64 + c0;
                    int s = jj8 >> 4, lo = jj8 & 15;
                    bf16x8 pk;
                    pk[0]=(short)f2bf(r0.x); pk[1]=(short)f2bf(r0.y); pk[2]=(short)f2bf(r0.z); pk[3]=(short)f2bf(r0.w);
                    pk[4]=(short)f2bf(r1.x); pk[5]=(short)f2bf(r1.y); pk[6]=(short)f2bf(r1.z); pk[7]=(short)f2bf(r1.w);
                    *(bf16x8*)&G[((((size_t)tt * LL + l) * 128 + s) * 64) + b * 16 + lo] = pk;
                }
            }
        }
    }
}

// ---------------- flag-tree barrier: per-block arrival flags + broadcast go word ----------------
DEV void fbar(unsigned int* flags, unsigned int* go, unsigned int ep)
{
    __syncthreads();   // drains this block's stores (vmcnt 0) before signaling
    int tid = threadIdx.x;
    if (blockIdx.x == 0){
        if (tid >= 1 && tid < PBLK){
            int g = 0;
            while (aldu(&flags[tid * 32]) < ep){
                if (++g > (1 << 24)) break;
                __builtin_amdgcn_s_sleep(1);
            }
        }
        __syncthreads();
        if (tid == 0) astu(go, ep);
    } else {
        if (tid == 0){
            astu(&flags[blockIdx.x * 32], ep);
            int g = 0;
            while (aldu(go) < ep){
                if (++g > (1 << 24)) break;
                __builtin_amdgcn_s_sleep(1);
            }
        }
        __syncthreads();
    }
    asm volatile("" ::: "memory");
}

// ---------------- persistent scan: 1 barrier/step, redundant cell+attn, reg-held G ----------------
// 128 blocks x 256 thr, all co-resident (<=1 block/CU needed on 256 CUs).
// Cross-block state: ONLY gates (double-buffered) + barrier words, via L3 atomics.
// hx/cx/alpha are block-local LDS (every block computes cell+attn redundantly).
__global__ __launch_bounds__(256) void scan_persist(
    const u16* __restrict__ G, const u16* __restrict__ whh_p,
    const float* __restrict__ bsum, const float* __restrict__ proj,
    const float* __restrict__ w_wT, const float* __restrict__ w_b,
    const float* __restrict__ waw, const float* __restrict__ wab,
    float* __restrict__ gates_g, unsigned int* __restrict__ flags,
    unsigned int* __restrict__ go, float* __restrict__ hseq)
{
    __shared__ float hxs[NB][HID];     // 8KB
    __shared__ float cxl[NB][HID];     // 8KB
    __shared__ float als[NB][LL];      // 3.75KB
    __shared__ float esl[NB][LL];      // 3.75KB
    __shared__ float red[16][NB][16];  // 4KB
    __shared__ float red2[NB][4][DD];  // 4KB
    __shared__ float apjs[NB][DD];     // 1KB

    int tid = threadIdx.x, blk = blockIdx.x;
    int jq = tid & 3, b = (tid >> 2) & 3, lg = tid >> 4;
    float wb0 = wab[0];

    // ---- init: hx=cx=0; alpha(0) locally; load G(0) slice into regs ----
    for (int i = tid; i < NB*HID; i += 256){ ((float*)hxs)[i] = 0.f; ((float*)cxl)[i] = 0.f; }
    { int b2 = tid >> 6, dd = tid & 63; apjs[b2][dd] = w_b[dd]; }
    __syncthreads();
    for (int b2 = 0; b2 < NB; b2++){
        if (tid < LL){
            const float4* pr = (const float4*)(proj + (((size_t)(b2*NT + 0)) * LL + tid) * DD);
            float e = 0.f;
#pragma unroll
            for (int d4 = 0; d4 < 16; d4++){
                float4 v = pr[d4];
                e = fmaf(tanh_f(v.x + apjs[b2][d4*4+0]), waw[d4*4+0], e);
                e = fmaf(tanh_f(v.y + apjs[b2][d4*4+1]), waw[d4*4+1], e);
                e = fmaf(tanh_f(v.z + apjs[b2][d4*4+2]), waw[d4*4+2], e);
                e = fmaf(tanh_f(v.w + apjs[b2][d4*4+3]), waw[d4*4+3], e);
            }
            esl[b2][tid] = e + wb0;
        }
    }
    __syncthreads();
    {
        int wv2 = tid >> 6, ln = tid & 63;
        float m = -1e30f;
        for (int l = ln; l < LL; l += 64) m = fmaxf(m, esl[wv2][l]);
#pragma unroll
        for (int off = 32; off; off >>= 1) m = fmaxf(m, __shfl_xor(m, off));
        float ex[4]; int c = 0; float ssum = 0.f;
        for (int l = ln; l < LL; l += 64){ float e2 = __expf(esl[wv2][l] - m); ex[c++] = e2; ssum += e2; }
#pragma unroll
        for (int off = 32; off; off >>= 1) ssum += __shfl_xor(ssum, off);
        float inv = 1.f / ssum; c = 0;
        for (int l = ln; l < LL; l += 64) als[wv2][l] = ex[c++] * inv;
    }

    short4 gregs[15];
    {
        const u16* gp = G + (size_t)blk * 64 + b * 16 + (jq << 2);
#pragma unroll
        for (int i = 0; i < 15; i++)
            gregs[i] = *(const short4*)(gp + (size_t)(lg * 15 + i) * 8192);
    }
    __syncthreads();

    for (int t = 0; t < NT; t++){
        float* gbuf = gates_g + (size_t)(t & 1) * (NB * NJ);

        // ---- gates: own 16-jj span from registers + whh from L2 ----
        float ac0 = 0.f, ac1 = 0.f, ac2 = 0.f, ac3 = 0.f;
#pragma unroll
        for (int i = 0; i < 15; i++){
            float al = als[b][lg * 15 + i];
            ac0 = fmaf(al, bf2f((u16)gregs[i].x), ac0);
            ac1 = fmaf(al, bf2f((u16)gregs[i].y), ac1);
            ac2 = fmaf(al, bf2f((u16)gregs[i].z), ac2);
            ac3 = fmaf(al, bf2f((u16)gregs[i].w), ac3);
        }
        {
            const u16* wp = whh_p + (size_t)(lg * 32) * NJ + blk * 16 + (jq << 2);
#pragma unroll 4
            for (int ki = 0; ki < 32; ki++){
                short4 wv = *(const short4*)(wp + (size_t)ki * NJ);
                float h = hxs[b][lg * 32 + ki];
                ac0 = fmaf(h, bf2f((u16)wv.x), ac0);
                ac1 = fmaf(h, bf2f((u16)wv.y), ac1);
                ac2 = fmaf(h, bf2f((u16)wv.z), ac2);
                ac3 = fmaf(h, bf2f((u16)wv.w), ac3);
            }
        }
        red[lg][b][(jq << 2) + 0] = ac0;
        red[lg][b][(jq << 2) + 1] = ac1;
        red[lg][b][(jq << 2) + 2] = ac2;
        red[lg][b][(jq << 2) + 3] = ac3;
        __syncthreads();
        if (tid < 64){
            int b2 = tid >> 4, jl = tid & 15;
            float v = 0.f;
#pragma unroll
            for (int q = 0; q < 16; q++) v += red[q][b2][jl];
            ast(&gbuf[(size_t)b2 * NJ + blk * 16 + jl], v);
        }
        fbar(flags, go, (unsigned int)(t + 1));

        // ---- prefetch G(t+1) into registers (completes under cell+attn) ----
        if (t < NT - 1){
            const u16* gp = G + ((size_t)(t + 1) * LL) * 8192 + (size_t)blk * 64 + b * 16 + (jq << 2);
#pragma unroll
            for (int i = 0; i < 15; i++)
                gregs[i] = *(const short4*)(gp + (size_t)(lg * 15 + i) * 8192);
        }

        // ---- cell (redundant in every block): full 4x512 units ----
        for (int i = tid; i < NB * HID; i += 256){
            int b2 = i >> 9, u = i & 511;
            float gi = ald(&gbuf[(size_t)b2 * NJ + u*4 + 0]);
            float gf = ald(&gbuf[(size_t)b2 * NJ + u*4 + 1]);
            float gg = ald(&gbuf[(size_t)b2 * NJ + u*4 + 2]);
            float go4 = ald(&gbuf[(size_t)b2 * NJ + u*4 + 3]);
            float4 bs = *(const float4*)&bsum[u*4];
            float c = sigm(gf + bs.y) * cxl[b2][u] + sigm(gi + bs.x) * tanhf(gg + bs.z);
            cxl[b2][u] = c;
            float h = sigm(go4 + bs.w) * tanhf(c);
            hxs[b2][u] = h;
            if (blk == 0) ast(&hseq[((size_t)t * NB + b2) * HID + u], h);
        }
        __syncthreads();

        if (t < NT - 1){
            // ---- attention(t+1) (redundant): apj gemv ----
            {
                int dd = tid & 63, dq = tid >> 6;
                float p0 = 0.f, p1 = 0.f, p2 = 0.f, p3 = 0.f;
                for (int ki = 0; ki < 128; ki++){
                    int k = dq * 128 + ki;
                    float wv = w_wT[k * 64 + dd];
                    p0 = fmaf(hxs[0][k], wv, p0);
                    p1 = fmaf(hxs[1][k], wv, p1);
                    p2 = fmaf(hxs[2][k], wv, p2);
                    p3 = fmaf(hxs[3][k], wv, p3);
                }
                red2[0][dq][dd] = p0; red2[1][dq][dd] = p1;
                red2[2][dq][dd] = p2; red2[3][dq][dd] = p3;
            }
            __syncthreads();
            {
                int b2 = tid >> 6, dd = tid & 63;
                apjs[b2][dd] = w_b[dd] + red2[b2][0][dd] + red2[b2][1][dd] + red2[b2][2][dd] + red2[b2][3][dd];
            }
            __syncthreads();
            for (int b2 = 0; b2 < NB; b2++){
                if (tid < LL){
                    const float4* pr = (const float4*)(proj + (((size_t)(b2*NT + t + 1)) * LL + tid) * DD);
                    float e = 0.f;
#pragma unroll
                    for (int d4 = 0; d4 < 16; d4++){
                        float4 v = pr[d4];
                        e = fmaf(tanh_f(v.x + apjs[b2][d4*4+0]), waw[d4*4+0], e);
                        e = fmaf(tanh_f(v.y + apjs[b2][d4*4+1]), waw[d4*4+1], e);
                        e = fmaf(tanh_f(v.z + apjs[b2][d4*4+2]), waw[d4*4+2], e);
                        e = fmaf(tanh_f(v.w + apjs[b2][d4*4+3]), waw[d4*4+3], e);
                    }
                    esl[b2][tid] = e + wb0;
                }
            }
            __syncthreads();
            {
                int wv2 = tid >> 6, ln = tid & 63;
                float m = -1e30f;
                for (int l = ln; l < LL; l += 64) m = fmaxf(m, esl[wv2][l]);
#pragma unroll
                for (int off = 32; off; off >>= 1) m = fmaxf(m, __shfl_xor(m, off));
                float ex[4]; int c = 0; float ssum = 0.f;
                for (int l = ln; l < LL; l += 64){ float e2 = __expf(esl[wv2][l] - m); ex[c++] = e2; ssum += e2; }
#pragma unroll
                for (int off = 32; off; off >>= 1) ssum += __shfl_xor(ssum, off);
                float inv = 1.f / ssum; c = 0;
                for (int l = ln; l < LL; l += 64) als[wv2][l] = ex[c++] * inv;
            }
            __syncthreads();
        }
    }
}

// ---------------- MLP heads ----------------
__global__ __launch_bounds__(256) void mlp_kernel(
    const float* __restrict__ hseq,
    const float* __restrict__ sw1T, const float* __restrict__ sb1,
    const float* __restrict__ sw2,  const float* __restrict__ sb2,
    const float* __restrict__ sw3,  const float* __restrict__ sb3,
    const float* __restrict__ sw4,  const float* __restrict__ sb4,
    const float* __restrict__ vw1T, const float* __restrict__ vb1,
    const float* __restrict__ vw2,  const float* __restrict__ vb2,
    const float* __restrict__ vw3,  const float* __restrict__ vb3,
    const float* __restrict__ vw4,  const float* __restrict__ vb4,
    float* __restrict__ out)
{
    __shared__ float h0[HID];
    __shared__ float h1[2][100];
    __shared__ float h2[2][52];
    __shared__ float h3[2][12];
    int tb = blockIdx.x;
    int tid = threadIdx.x;
    for (int i = tid; i < HID; i += 256) h0[i] = hseq[(size_t)tb * HID + i];
    __syncthreads();
    if (tid < 100){
        float a = sb1[tid];
        for (int k = 0; k < HID; k++) a = fmaf(h0[k], sw1T[k*100 + tid], a);
        h1[0][tid] = fmaxf(a, 0.f);
    } else if (tid >= 128 && tid < 228){
        int u = tid - 128;
        float a = vb1[u];
        for (int k = 0; k < HID; k++) a = fmaf(h0[k], vw1T[k*100 + u], a);
        h1[1][u] = fmaxf(a, 0.f);
    }
    __syncthreads();
    if (tid < 50){
        float a = sb2[tid];
        for (int k = 0; k < 100; k++) a = fmaf(h1[0][k], sw2[tid*100 + k], a);
        h2[0][tid] = fmaxf(a, 0.f);
    } else if (tid >= 128 && tid < 178){
        int u = tid - 128;
        float a = vb2[u];
        for (int k = 0; k < 100; k++) a = fmaf(h1[1][k], vw2[u*100 + k], a);
        h2[1][u] = fmaxf(a, 0.f);
    }
    __syncthreads();
    if (tid < 10){
        float a = sb3[tid];
        for (int k = 0; k < 50; k++) a = fmaf(h2[0][k], sw3[tid*50 + k], a);
        h3[0][tid] = fmaxf(a, 0.f);
    } else if (tid >= 128 && tid < 138){
        int u = tid - 128;
        float a = vb3[u];
        for (int k = 0; k < 50; k++) a = fmaf(h2[1][k], vw3[u*50 + k], a);
        h3[1][u] = fmaxf(a, 0.f);
    }
    __syncthreads();
    if (tid == 0){
        float a = sb4[0];
        for (int k = 0; k < 10; k++) a = fmaf(h3[0][k], sw4[k], a);
        out[tb] = a;
    } else if (tid == 128){
        float a = vb4[0];
        for (int k = 0; k < 10; k++) a = fmaf(h3[1][k], vw4[k], a);
        out[360 + tb] = a;
    }
}

extern "C" void kernel_launch(void* const* d_in, const int* in_sizes, int n_in,
                              void* d_out, int out_size, void* d_ws, size_t ws_size,
                              hipStream_t stream)
{
    (void)in_sizes; (void)n_in; (void)out_size;
    if (ws_size < WS_NEEDED) return;

    const float* cam   = (const float*)d_in[0];
    const float* cw1   = (const float*)d_in[1];  const float* cb1 = (const float*)d_in[2];
    const float* cw2   = (const float*)d_in[3];  const float* cb2 = (const float*)d_in[4];
    const float* cw3   = (const float*)d_in[5];  const float* cb3 = (const float*)d_in[6];
    const float* cw4   = (const float*)d_in[7];  const float* cb4 = (const float*)d_in[8];
    const float* cw5   = (const float*)d_in[9];  const float* cb5 = (const float*)d_in[10];
    const float* pw    = (const float*)d_in[11]; const float* pb  = (const float*)d_in[12];
    const float* w_w   = (const float*)d_in[13]; const float* w_b = (const float*)d_in[14];
    const float* waw   = (const float*)d_in[15]; const float* wab = (const float*)d_in[16];
    const float* wih   = (const float*)d_in[17]; const float* whh = (const float*)d_in[18];
    const float* bih   = (const float*)d_in[19]; const float* bhh = (const float*)d_in[20];
    const float* sw1   = (const float*)d_in[21]; const float* sb1 = (const float*)d_in[22];
    const float* sw2   = (const float*)d_in[23]; const float* sb2 = (const float*)d_in[24];
    const float* sw3   = (const float*)d_in[25]; const float* sb3 = (const float*)d_in[26];
    const float* sw4   = (const float*)d_in[27]; const float* sb4 = (const float*)d_in[28];
    const float* vw1   = (const float*)d_in[29]; const float* vb1 = (const float*)d_in[30];
    const float* vw2   = (const float*)d_in[31]; const float* vb2 = (const float*)d_in[32];
    const float* vw3   = (const float*)d_in[33]; const float* vb3 = (const float*)d_in[34];
    const float* vw4   = (const float*)d_in[35]; const float* vb4 = (const float*)d_in[36];

    char* ws = (char*)d_ws;
    u16*   camcl = (u16*)(ws + CAMCL_OFF);
    u16*   a1    = (u16*)(ws + A1_OFF);
    u16*   a2    = (u16*)(ws + A2_OFF);
    u16*   a3    = (u16*)(ws + A3_OFF);
    u16*   a4    = (u16*)(ws + A4_OFF);
    u16*   a5    = (u16*)(ws + A5_OFF);
    u16*   w1b   = (u16*)(ws + W1B_OFF);
    u16*   w2b   = (u16*)(ws + W2B_OFF);
    u16*   w3b   = (u16*)(ws + W3B_OFF);
    u16*   w4b   = (u16*)(ws + W4B_OFF);
    u16*   w5b   = (u16*)(ws + W5B_OFF);
    float* feats = (float*)(ws + FEATS_OFF);
    float* proj  = (float*)(ws + PROJ_OFF);
    float* w_wT  = (float*)(ws + WWT_OFF);
    u16*   whh_p = (u16*)  (ws + WHHP_OFF);
    float* bsum  = (float*)(ws + BSUM_OFF);
    float* sw1T  = (float*)(ws + SW1T_OFF);
    float* vw1T  = (float*)(ws + VW1T_OFF);
    float* gates_g = (float*)(ws + SC_GATES);
    unsigned int* flags = (unsigned int*)(ws + SC_FLAGS);
    unsigned int* go    = (unsigned int*)(ws + SC_GO);
    float* hseq  = (float*)(ws + HSEQ_OFF);
    u16*   G     = (u16*)  (ws + G_OFF);

    cam_to_cl<<<(NIMG*96*160 + 255)/256, 256, 0, stream>>>(cam, camcl);
    prep_wbf<<<64, 256, 0, stream>>>(cw1, w1b, 24,  3,  8, 5, 28, 32);
    prep_wbf<<<64, 256, 0, stream>>>(cw2, w2b, 36, 24, 24, 5, 28, 48);
    prep_wbf<<<64, 256, 0, stream>>>(cw3, w3b, 48, 36, 40, 5, 28, 48);
    prep_wbf<<<64, 256, 0, stream>>>(cw4, w4b, 64, 48, 48, 3, 10, 64);
    prep_wbf<<<64, 256, 0, stream>>>(cw5, w5b, 64, 64, 64, 3,  9, 64);

    conv_mfma<   8,    32,   24,  24,   5,  28,   2, 2, 96, 160, 48, 80,  8, 40>
        <<<dim3(12, NIMG), 256, 0, stream>>>(camcl, w1b, cb1, a1);
    conv_mfma<  24,    48,   36,  40,   5,  28,   2, 2, 48,  80, 24, 40,  8, 20>
        <<<dim3(6, NIMG), 256, 0, stream>>>(a1, w2b, cb2, a2);
    conv_mfma<  40,    48,   48,  48,   5,  28,   2, 2, 24,  40, 12, 20, 12, 20>
        <<<dim3(1, NIMG), 256, 0, stream>>>(a2, w3b, cb3, a3);
    conv_mfma<  48,    64,   64,  64,   3,  10,   1, 1, 12,  20, 12, 20, 12, 20>
        <<<dim3(1, NIMG), 256, 0, stream>>>(a3, w4b, cb4, a4);
    conv_mfma<  64,    64,   64,  64,   3,   9,   1, 1, 12,  20, 12, 20, 12, 20>
        <<<dim3(1, NIMG), 256, 0, stream>>>(a4, w5b, cb5, a5);

    extract_feats<<<(NIMG*12*20*64 + 255)/256, 256, 0, stream>>>(a5, feats);
    proj_kernel<<<NIMG*LL/4, 256, 0, stream>>>(feats, pw, pb, proj);
    prep<<<1024, 256, 0, stream>>>(w_w, whh, bih, bhh, w_wT, whh_p, bsum);
    gcompute_mfma2<<<dim3(8, 240), 256, 0, stream>>>(feats, wih, G);

    // zero scan state (gates dbl-buf + flags + go) -- feats dead; re-zeroed every replay
    hipMemsetAsync(ws + SC_GATES, 0, 82048, stream);

    scan_persist<<<PBLK, 256, 0, stream>>>(G, whh_p, bsum, proj, w_wT, w_b, waw, wab,
                                           gates_g, flags, go, hseq);

    prep2<<<256, 256, 0, stream>>>(sw1, vw1, sw1T, vw1T);

    mlp_kernel<<<360, 256, 0, stream>>>(hseq,
        sw1T, sb1, sw2, sb2, sw3, sb3, sw4, sb4,
        vw1T, vb1, vw2, vb2, vw3, vb3, vw4, vb4, (float*)d_out);
}

// Round 8
// 2246.517 us; speedup vs baseline: 1.7466x; 1.7466x over previous
//
#include <hip/hip_runtime.h>
#include <hip/hip_bf16.h>

typedef unsigned short u16;
using bf16x8 = __attribute__((ext_vector_type(8))) short;
using f32x4  = __attribute__((ext_vector_type(4))) float;

#define NB   4
#define NT   90
#define NIMG 360
#define LL   240
#define DD   64
#define HID  512
#define NJ   2048
#define GBLK 64          // gates blocks
#define TBLK (GBLK + NB) // total persistent blocks = 68

#define DEV __device__ __forceinline__

DEV float bf2f(u16 x){ unsigned int u = ((unsigned int)x) << 16; float f; __builtin_memcpy(&f, &u, 4); return f; }
DEV u16 f2bf(float f){ unsigned int u; __builtin_memcpy(&u, &f, 4); unsigned int r = (u + 0x7FFFu + ((u >> 16) & 1u)) >> 16; return (u16)r; }
DEV float sigm(float x){ return 1.f / (1.f + __expf(-x)); }
DEV float tanh_f(float x){ x = fminf(fmaxf(x, -15.f), 15.f); float e = __expf(2.f*x); return (e - 1.f) / (e + 1.f); }

// L3-coherent (agent-scope, relaxed) accessors for cross-XCD mutable state.
DEV void  ast(float* p, float v){ __hip_atomic_store(p, v, __ATOMIC_RELAXED, __HIP_MEMORY_SCOPE_AGENT); }
DEV float ald(const float* p){ return __hip_atomic_load(p, __ATOMIC_RELAXED, __HIP_MEMORY_SCOPE_AGENT); }
DEV void  astu(unsigned int* p, unsigned int v){ __hip_atomic_store(p, v, __ATOMIC_RELAXED, __HIP_MEMORY_SCOPE_AGENT); }
DEV unsigned int aldu(const unsigned int* p){ return __hip_atomic_load(p, __ATOMIC_RELAXED, __HIP_MEMORY_SCOPE_AGENT); }

// ---------------- workspace layout (bytes) ----------------
static const size_t G_OFF     = 0;            // u16 [90][240][128][64] (span-major) = 353,894,400 B
static const size_t CAMCL_OFF = 0;            // conv temporaries alias over G
static const size_t A1_OFF    = 88473600;
static const size_t A2_OFF    = 154828800;
static const size_t A3_OFF    = 182476800;
static const size_t A4_OFF    = 190771200;
static const size_t A5_OFF    = 201830400;
static const size_t W1B_OFF   = 212889600;
static const size_t W2B_OFF   = 212903936;
static const size_t W3B_OFF   = 212968448;
static const size_t W4B_OFF   = 213075968;
static const size_t W5B_OFF   = 213137408;
static const size_t FEATS_OFF = 353894400;    // fp32 [360][240][64]; dead during scan
static const size_t SC_GBUF   = 353894400;    // fp32 [4][2048] = 32KB
static const size_t SC_ALPHA  = 353927168;    // fp32 [4][240] (4KB slot)
static const size_t SC_HX     = 353931264;    // fp32 [4][512] = 8KB
static const size_t SC_CTR    = 353939456;    // u32 [8][32] = 1KB (per-XCD arrival counters)
static const size_t SC_RDY    = 353940480;    // u32 [4] in one 128B line
static const size_t PROJ_OFF  = 376012800;    // fp32 [360][240][64]
static const size_t WWT_OFF   = 398131200;    // fp32 [512][64]   w_w^T
static const size_t WHHP_OFF  = 398262272;    // bf16 [512][2048] whh^T, j-permuted
static const size_t BSUM_OFF  = 400359424;    // fp32 [2048] bih+bhh, j-permuted
static const size_t SW1T_OFF  = 400367616;    // fp32 [512][100]
static const size_t VW1T_OFF  = 400572416;    // fp32 [512][100]
static const size_t HSEQ_OFF  = 400809984;    // fp32 [90][4][512]
static const size_t WS_NEEDED = 401547264;

// ---------------- camera NCHW fp32 -> channels-last bf16 [n][h][w][8] ----------------
__global__ __launch_bounds__(256) void cam_to_cl(const float* __restrict__ cam, u16* __restrict__ out)
{
    int i = blockIdx.x * 256 + threadIdx.x;
    if (i >= NIMG * 96 * 160) return;
    int hw = i % (96 * 160);
    int n  = i / (96 * 160);
    const float* p = cam + (size_t)n * 3 * 96 * 160 + hw;
    bf16x8 v;
    v[0] = (short)f2bf(p[0]);
    v[1] = (short)f2bf(p[15360]);
    v[2] = (short)f2bf(p[30720]);
    v[3] = 0; v[4] = 0; v[5] = 0; v[6] = 0; v[7] = 0;
    *(bf16x8*)&out[(size_t)i * 8] = v;
}

// ---------------- weight prep for convs ----------------
__global__ __launch_bounds__(256) void prep_wbf(
    const float* __restrict__ w, u16* __restrict__ wbf,
    int COUT, int CIN, int CI_PAD, int KHW, int CELLS_PAD, int M_PAD)
{
    int K_PAD = CELLS_PAD * CI_PAD;
    int total = M_PAD * K_PAD;
    for (int i = blockIdx.x * 256 + threadIdx.x; i < total; i += gridDim.x * 256){
        int co = i / K_PAD, kk = i % K_PAD;
        int cell = kk / CI_PAD, ci = kk % CI_PAD;
        float v = 0.f;
        if (co < COUT && cell < KHW * KHW && ci < CIN){
            int kh = cell / KHW, kw = cell % KHW;
            v = w[((size_t)(co * CIN + ci) * KHW + kh) * KHW + kw];
        }
        wbf[i] = f2bf(v);
    }
}

// ---------------- implicit-GEMM MFMA conv (channels-last bf16 in/out) ----------------
template<int CI_PAD, int M_PAD, int COUT, int CO_STORE, int KHW, int CELLS_PAD,
         int S, int P, int HIN, int WIN, int HOUT, int WOUT, int TOH, int TOW>
__global__ __launch_bounds__(256) void conv_mfma(
    const u16* __restrict__ in, const u16* __restrict__ wbf,
    const float* __restrict__ bias, u16* __restrict__ out)
{
    constexpr int K_PAD = CELLS_PAD * CI_PAD;
    constexpr int CP8   = CI_PAD / 8;
    constexpr int TIH   = (TOH - 1) * S + KHW;
    constexpr int TIW   = (TOW - 1) * S + KHW;
    constexpr int TIW_H = (TIW + 1) / 2;
    constexpr int NF    = TOH * TOW / 16;
    constexpr int NK0   = K_PAD / 32;
    constexpr int MF    = M_PAD / 16;
    constexpr int NPW   = (NF + 3) / 4;
    constexpr int LDSE  = (S == 2) ? TIH * CP8 * 2 * TIW_H * 8 : TIH * CP8 * TIW * 8;
    static_assert((TOH * TOW) % 16 == 0, "N tile");
    static_assert(K_PAD % 32 == 0, "K pad");

    __shared__ u16 lds[LDSE];

    int tile = blockIdx.x, n = blockIdx.y;
    constexpr int TW_T = WOUT / TOW;
    int th = tile / TW_T, tw = tile % TW_T;
    int oh0 = th * TOH, ow0 = tw * TOW;
    int ih0 = oh0 * S - P, iw0 = ow0 * S - P;
    int tid = threadIdx.x;

    constexpr int CHUNKS = TIH * TIW * CP8;
    for (int i = tid; i < CHUNKS; i += 256){
        int c8 = i % CP8; int r2 = i / CP8;
        int iw = r2 % TIW, ih = r2 / TIW;
        int ihg = ih0 + ih, iwg = iw0 + iw;
        bf16x8 v = {0,0,0,0,0,0,0,0};
        if (ihg >= 0 && ihg < HIN && iwg >= 0 && iwg < WIN)
            v = *(const bf16x8*)&in[(((size_t)n * HIN + ihg) * WIN + iwg) * CI_PAD + c8 * 8];
        int off;
        if (S == 2) off = (((ih * CP8 + c8) * 2 + (iw & 1)) * TIW_H + (iw >> 1)) * 8;
        else        off = ((ih * CP8 + c8) * TIW + iw) * 8;
        *(bf16x8*)&lds[off] = v;
    }
    __syncthreads();

    int lane = tid & 63, wv = tid >> 6;
    int col = lane & 15, grp = lane >> 4;

    int ihb[NPW], iwb[NPW];
    bool act[NPW];
#pragma unroll
    for (int i2 = 0; i2 < NPW; i2++){
        int nf = wv + i2 * 4;
        act[i2] = (nf < NF);
        int nfc = act[i2] ? nf : 0;
        int nsp = nfc * 16 + col;
        ihb[i2] = (nsp / TOW) * S;
        iwb[i2] = (nsp % TOW) * S;
    }

    f32x4 acc[MF][NPW];
#pragma unroll
    for (int mf = 0; mf < MF; mf++)
#pragma unroll
        for (int i2 = 0; i2 < NPW; i2++)
            acc[mf][i2] = (f32x4){0.f, 0.f, 0.f, 0.f};

    for (int k0 = 0; k0 < NK0; k0++){
        bf16x8 a[MF];
#pragma unroll
        for (int mf = 0; mf < MF; mf++)
            a[mf] = *(const bf16x8*)&wbf[(size_t)(mf * 16 + col) * K_PAD + k0 * 32 + grp * 8];
        int k8 = k0 * 32 + grp * 8;
        int cell = k8 / CI_PAD;
        int ci0  = k8 - cell * CI_PAD;
        if (cell >= KHW * KHW) cell = 0;
        int kh = cell / KHW, kw = cell - (cell / KHW) * KHW;
        int cb = ci0 >> 3;
#pragma unroll
        for (int i2 = 0; i2 < NPW; i2++){
            if (!act[i2]) continue;
            int ih = ihb[i2] + kh;
            int off;
            if (S == 2) off = (((ih * CP8 + cb) * 2 + (kw & 1)) * TIW_H + (iwb[i2] >> 1) + (kw >> 1)) * 8;
            else        off = ((ih * CP8 + cb) * TIW + iwb[i2] + kw) * 8;
            bf16x8 b = *(const bf16x8*)&lds[off];
#pragma unroll
            for (int mf = 0; mf < MF; mf++)
                acc[mf][i2] = __builtin_amdgcn_mfma_f32_16x16x32_bf16(a[mf], b, acc[mf][i2], 0, 0, 0);
        }
    }

#pragma unroll
    for (int i2 = 0; i2 < NPW; i2++){
        if (!act[i2]) continue;
        int nf = wv + i2 * 4;
        int nsp = nf * 16 + col;
        int oh = oh0 + nsp / TOW, ow = ow0 + nsp % TOW;
        size_t obase = (((size_t)n * HOUT + oh) * WOUT + ow) * CO_STORE;
#pragma unroll
        for (int mf = 0; mf < MF; mf++){
            int cobase = mf * 16 + grp * 4;
#pragma unroll
            for (int r = 0; r < 4; r++){
                int co = cobase + r;
                if (co < CO_STORE){
                    float x = (co < COUT) ? fmaxf(acc[mf][i2][r] + bias[co], 0.f) : 0.f;
                    out[obase + co] = f2bf(x);
                }
            }
        }
    }
}

// ---------------- feats rearrange ----------------
__global__ __launch_bounds__(256) void extract_feats(const u16* __restrict__ a5, float* __restrict__ feats)
{
    int idx = blockIdx.x * 256 + threadIdx.x;
    if (idx >= NIMG * 12 * 20 * 64) return;
    int c = idx & 63; int t1 = idx >> 6;
    int w = t1 % 20; t1 /= 20;
    int h = t1 % 12; int n = t1 / 12;
    float v = bf2f(a5[idx]);
    int flat = w * 768 + c * 12 + h;
    int d = flat / 240, l = flat % 240;
    feats[((size_t)n * LL + l) * DD + d] = v;
}

// ---------------- proj = feats @ proj_w.T + proj_b ----------------
__global__ __launch_bounds__(256) void proj_kernel(
    const float* __restrict__ feats, const float* __restrict__ pw,
    const float* __restrict__ pb, float* __restrict__ proj)
{
    __shared__ float pws[64][65];
    __shared__ float fs[4][64];
    int tid = threadIdx.x;
    size_t R0 = (size_t)blockIdx.x * 4;
    for (int i = tid; i < 4096; i += 256){
        int dd = i / 64, d = i % 64;
        pws[d][dd] = pw[dd*64 + d];
    }
    { int r = tid / 64, d = tid % 64; fs[r][d] = feats[(R0 + r)*64 + d]; }
    __syncthreads();
    int r = tid / 64, dd = tid % 64;
    float a = pb[dd];
    for (int d = 0; d < 64; d++) a = fmaf(fs[r][d], pws[d][dd], a);
    proj[(R0 + r)*64 + dd] = a;
}

// ---------------- prep: whh permute, bias combine, w_w transpose ----------------
__global__ __launch_bounds__(256) void prep(
    const float* __restrict__ w_w, const float* __restrict__ whh,
    const float* __restrict__ bih, const float* __restrict__ bhh,
    float* __restrict__ w_wT, u16* __restrict__ whh_p, float* __restrict__ bsum)
{
    int idx = blockIdx.x * 256 + threadIdx.x;
    int stride = gridDim.x * 256;
    for (int i = idx; i < 512*64; i += stride){
        int k = i / 64, dd = i % 64;
        w_wT[i] = w_w[dd*512 + k];
    }
    for (int i = idx; i < 512*2048; i += stride){
        int k = i / 2048, jj = i % 2048;
        int u = jj >> 2, g = jj & 3, j = g*512 + u;
        whh_p[i] = f2bf(whh[(size_t)j*512 + k]);
    }
    for (int i = idx; i < 2048; i += stride){
        int u = i >> 2, g = i & 3, j = g*512 + u;
        bsum[i] = bih[j] + bhh[j];
    }
}

// ---------------- prep2: MLP first-layer transposes ----------------
__global__ __launch_bounds__(256) void prep2(
    const float* __restrict__ sw1, const float* __restrict__ vw1,
    float* __restrict__ sw1T, float* __restrict__ vw1T)
{
    int idx = blockIdx.x * 256 + threadIdx.x;
    int stride = gridDim.x * 256;
    for (int i = idx; i < 512*100; i += stride){
        int k = i / 100, u = i % 100;
        sw1T[i] = sw1[u*512 + k];
        vw1T[i] = vw1[u*512 + k];
    }
}

// ---------------- gcompute via MFMA (G span-major: [((t*240+l)*128+s)*64 + b*16 + lo]) --------
__global__ __launch_bounds__(256, 2) void gcompute_mfma2(
    const float* __restrict__ feats, const float* __restrict__ wih, u16* __restrict__ G)
{
    __shared__ u16 Bsw[256 * 64];
    __shared__ u16 Asw[128 * 64];
    float (*obuf)[1024] = (float(*)[1024])Asw;

    int jt = blockIdx.x, l = blockIdx.y;
    int j0 = jt * 256;
    int tid = threadIdx.x;
    int g8 = tid & 7;

    for (int p = 0; p < 8; p++){
        int row = p * 32 + (tid >> 3);
        int jj = j0 + row;
        int j = (jj & 3) * 512 + (jj >> 2);
        const float* src = wih + (size_t)j * 15360 + l * 64 + g8 * 8;
        float4 v0 = *(const float4*)src;
        float4 v1 = *(const float4*)(src + 4);
        bf16x8 pk;
        pk[0]=(short)f2bf(v0.x); pk[1]=(short)f2bf(v0.y); pk[2]=(short)f2bf(v0.z); pk[3]=(short)f2bf(v0.w);
        pk[4]=(short)f2bf(v1.x); pk[5]=(short)f2bf(v1.y); pk[6]=(short)f2bf(v1.z); pk[7]=(short)f2bf(v1.w);
        *(bf16x8*)&Bsw[(row * 8 + (g8 ^ (row & 7))) * 8] = pk;
    }
    __syncthreads();

    int lane = tid & 63, w = tid >> 6;
    int col = lane & 15, grp = lane >> 4;

    bf16x8 bfr[2][4];
#pragma unroll
    for (int k0 = 0; k0 < 2; k0++)
#pragma unroll
        for (int nf = 0; nf < 4; nf++){
            int row = w * 64 + nf * 16 + col;
            bfr[k0][nf] = *(const bf16x8*)&Bsw[(row * 8 + ((k0 * 4 + grp) ^ (row & 7))) * 8];
        }

    for (int mt = 0; mt < 3; mt++){
        int m0 = mt * 128;
        __syncthreads();
        for (int p = 0; p < 4; p++){
            int row = p * 32 + (tid >> 3);
            const float* src = feats + ((size_t)(m0 + row) * LL + l) * DD + g8 * 8;
            float4 v0 = *(const float4*)src;
            float4 v1 = *(const float4*)(src + 4);
            bf16x8 pk;
            pk[0]=(short)f2bf(v0.x); pk[1]=(short)f2bf(v0.y); pk[2]=(short)f2bf(v0.z); pk[3]=(short)f2bf(v0.w);
            pk[4]=(short)f2bf(v1.x); pk[5]=(short)f2bf(v1.y); pk[6]=(short)f2bf(v1.z); pk[7]=(short)f2bf(v1.w);
            *(bf16x8*)&Asw[(row * 8 + (g8 ^ (row & 7))) * 8] = pk;
        }
        __syncthreads();

        f32x4 acc[8][4];
#pragma unroll
        for (int mf = 0; mf < 8; mf++)
#pragma unroll
            for (int nf = 0; nf < 4; nf++) acc[mf][nf] = (f32x4){0.f,0.f,0.f,0.f};

#pragma unroll
        for (int k0 = 0; k0 < 2; k0++){
#pragma unroll
            for (int mf = 0; mf < 8; mf++){
                int row = mf * 16 + col;
                bf16x8 a = *(const bf16x8*)&Asw[(row * 8 + ((k0 * 4 + grp) ^ (row & 7))) * 8];
#pragma unroll
                for (int nf = 0; nf < 4; nf++)
                    acc[mf][nf] = __builtin_amdgcn_mfma_f32_16x16x32_bf16(a, bfr[k0][nf], acc[mf][nf], 0, 0, 0);
            }
        }
        __syncthreads();

#pragma unroll
        for (int mf = 0; mf < 8; mf++){
#pragma unroll
            for (int nf = 0; nf < 4; nf++)
#pragma unroll
                for (int r = 0; r < 4; r++)
                    obuf[w][(grp * 4 + r) * 64 + nf * 16 + col] = acc[mf][nf][r];
#pragma unroll
            for (int p = 0; p < 2; p++){
                int rloc = p * 8 + (lane >> 3);
                int c0 = (lane & 7) * 8;
                float4 r0 = *(const float4*)&obuf[w][rloc * 64 + c0];
                float4 r1 = *(const float4*)&obuf[w][rloc * 64 + c0 + 4];
                int m = m0 + mf * 16 + rloc;
                if (m < NIMG){
                    int b = m / NT, tt = m % NT;
                    int jj8 = j0 + w * 64 + c0;
                    int s = jj8 >> 4, lo = jj8 & 15;
                    bf16x8 pk;
                    pk[0]=(short)f2bf(r0.x); pk[1]=(short)f2bf(r0.y); pk[2]=(short)f2bf(r0.z); pk[3]=(short)f2bf(r0.w);
                    pk[4]=(short)f2bf(r1.x); pk[5]=(short)f2bf(r1.y); pk[6]=(short)f2bf(r1.z); pk[7]=(short)f2bf(r1.w);
                    *(bf16x8*)&G[((((size_t)tt * LL + l) * 128 + s) * 64) + b * 16 + lo] = pk;
                }
            }
        }
    }
}

// ---------------- persistent producer-consumer scan (68 blocks) ----------------
// blk 0-3: cell+attention for batch blk (cx local; publishes hx, alpha, ready[b]).
// blk 4-67: gates for jj span (blk-4)*32 (publishes gates slice, per-XCD arrival counter).
// Handshake per step: gates wait ready-line >= t+1; cell waits 8 XCD counters == 8(t+1).
// Single-buffered gbuf/alpha/hx: every overwrite happens strictly after its readers retired.
__global__ __launch_bounds__(256) void scan_pc(
    const u16* __restrict__ G, const u16* __restrict__ whh_p,
    const float* __restrict__ bsum, const float* __restrict__ proj,
    const float* __restrict__ w_wT, const float* __restrict__ w_b,
    const float* __restrict__ waw, const float* __restrict__ wab,
    float* __restrict__ gbuf, float* __restrict__ alpha_g, float* __restrict__ hx_g,
    unsigned int* __restrict__ ctr, unsigned int* __restrict__ rdy,
    float* __restrict__ hseq)
{
    int tid = threadIdx.x, blk = blockIdx.x;

    if (blk < NB){
        // ================= CELL BLOCK (batch b) =================
        __shared__ float projL[LL * DD];   // 60KB proj(t+1) slice
        __shared__ float cxl[HID];
        __shared__ float hloc[HID];
        __shared__ float red2[4][DD];
        __shared__ float apjs[DD];
        __shared__ float esl[LL];
        int b = blk;
        float wb0 = wab[0];

        // init: stage proj(0); publish hx(-1)=0; alpha(0); ready=1
        {
            const float* src = proj + ((size_t)(b * NT + 0)) * LL * DD;
            for (int it = 0; it < 15; it++){
                int idx = it * 256 + tid;
                *(float4*)&projL[idx * 4] = *(const float4*)&src[idx * 4];
            }
        }
        cxl[tid] = 0.f; cxl[tid + 256] = 0.f;
        ast(&hx_g[b * HID + tid], 0.f);
        ast(&hx_g[b * HID + tid + 256], 0.f);
        if (tid < DD) apjs[tid] = w_b[tid];
        __syncthreads();
        if (tid < LL){
            const float* pr = &projL[tid * DD];
            float e = 0.f;
#pragma unroll
            for (int d = 0; d < DD; d++) e = fmaf(tanh_f(pr[d] + apjs[d]), waw[d], e);
            esl[tid] = e + wb0;
        }
        __syncthreads();
        if (tid < 64){
            float m = -1e30f;
            for (int l = tid; l < LL; l += 64) m = fmaxf(m, esl[l]);
#pragma unroll
            for (int off = 32; off; off >>= 1) m = fmaxf(m, __shfl_xor(m, off));
            float ex[4]; int c = 0; float ssum = 0.f;
            for (int l = tid; l < LL; l += 64){ float e2 = __expf(esl[l] - m); ex[c++] = e2; ssum += e2; }
#pragma unroll
            for (int off = 32; off; off >>= 1) ssum += __shfl_xor(ssum, off);
            float inv = 1.f / ssum; c = 0;
            for (int l = tid; l < LL; l += 64) ast(&alpha_g[b * LL + l], ex[c++] * inv);
        }
        __syncthreads();
        if (tid == 0) astu(&rdy[b], 1u);

        for (int t = 0; t < NT; t++){
            // stage proj(t+1) while gates blocks work
            if (t < NT - 1){
                const float* src = proj + ((size_t)(b * NT + t + 1)) * LL * DD;
                for (int it = 0; it < 15; it++){
                    int idx = it * 256 + tid;
                    *(float4*)&projL[idx * 4] = *(const float4*)&src[idx * 4];
                }
            }
            // wait all 8 XCD counters at 8(t+1)
            if (tid < 8){
                unsigned int tgt = 8u * (t + 1);
                int g = 0;
                while (aldu(&ctr[tid * 32]) < tgt){
                    if (++g > (1 << 22)) break;
                    __builtin_amdgcn_s_sleep(1);
                }
            }
            __syncthreads();

            // cell(t): 2 units per thread
#pragma unroll
            for (int q = 0; q < 2; q++){
                int u = q * 256 + tid;
                float gi = ald(&gbuf[(size_t)b * NJ + u*4 + 0]);
                float gf = ald(&gbuf[(size_t)b * NJ + u*4 + 1]);
                float gg = ald(&gbuf[(size_t)b * NJ + u*4 + 2]);
                float go = ald(&gbuf[(size_t)b * NJ + u*4 + 3]);
                float4 bs = *(const float4*)&bsum[u*4];
                float c = sigm(gf + bs.y) * cxl[u] + sigm(gi + bs.x) * tanhf(gg + bs.z);
                cxl[u] = c;
                float h = sigm(go + bs.w) * tanhf(c);
                hloc[u] = h;
                ast(&hx_g[b * HID + u], h);
                hseq[((size_t)t * NB + b) * HID + u] = h;  // plain store; flushed at kernel end
            }
            __syncthreads();
            if (t == NT - 1) break;

            // attention(t+1): apj gemv then es/softmax from LDS proj
            {
                int dd = tid & 63, dq = tid >> 6;
                float p = 0.f;
                for (int ki = 0; ki < 128; ki++){
                    int k = dq * 128 + ki;
                    p = fmaf(hloc[k], w_wT[k * 64 + dd], p);
                }
                red2[dq][dd] = p;
            }
            __syncthreads();
            if (tid < 64) apjs[tid] = w_b[tid] + red2[0][tid] + red2[1][tid] + red2[2][tid] + red2[3][tid];
            __syncthreads();
            if (tid < LL){
                const float* pr = &projL[tid * DD];
                float e = 0.f;
#pragma unroll
                for (int d = 0; d < DD; d++) e = fmaf(tanh_f(pr[d] + apjs[d]), waw[d], e);
                esl[tid] = e + wb0;
            }
            __syncthreads();
            if (tid < 64){
                float m = -1e30f;
                for (int l = tid; l < LL; l += 64) m = fmaxf(m, esl[l]);
#pragma unroll
                for (int off = 32; off; off >>= 1) m = fmaxf(m, __shfl_xor(m, off));
                float ex[4]; int c = 0; float ssum = 0.f;
                for (int l = tid; l < LL; l += 64){ float e2 = __expf(esl[l] - m); ex[c++] = e2; ssum += e2; }
#pragma unroll
                for (int off = 32; off; off >>= 1) ssum += __shfl_xor(ssum, off);
                float inv = 1.f / ssum; c = 0;
                for (int l = tid; l < LL; l += 64) ast(&alpha_g[b * LL + l], ex[c++] * inv);
            }
            __syncthreads();          // drains alpha/hx stores (vmcnt 0)
            if (tid == 0) astu(&rdy[b], (unsigned int)(t + 2));
        }
    } else {
        // ================= GATES BLOCK (span s) =================
        __shared__ float als[NB][LL];      // 3.75KB
        __shared__ float hxs[NB][HID];     // 8KB
        __shared__ float red[8][NB][32];   // 4KB
        int s = blk - NB;
        int jj0 = s * 32;
        int jq = tid & 7, b = (tid >> 3) & 3, lg = tid >> 5;
        int jjl = jq * 4;
        int span16 = 2 * s + (jjl >> 4);
        int lo = jjl & 15;

        // prefetch G(0) into own-XCD L2 (touch both 128B lines per l)
        {
            float sink = 0.f;
            if (tid < LL){
                const u16* gp = G + (((size_t)0 * LL + tid) * 128 + 2 * s) * 64;
                sink += (float)gp[0] + (float)gp[64];
            }
            asm volatile("" :: "v"(sink));
        }

        for (int t = 0; t < NT; t++){
            // wait ready line >= t+1 (4 words, 4 plain-store writers)
            if (tid < 4){
                int g = 0;
                while (aldu(&rdy[tid]) < (unsigned int)(t + 1)){
                    if (++g > (1 << 22)) break;
                    __builtin_amdgcn_s_sleep(1);
                }
            }
            __syncthreads();

            // stage alpha(t) + hx(t-1)
            for (int i = tid; i < NB * LL; i += 256) ((float*)als)[i] = ald(&alpha_g[i]);
            for (int i = tid; i < NB * HID; i += 256) ((float*)hxs)[i] = ald(&hx_g[i]);
            __syncthreads();

            // gates partial: sum_l alpha*G (30 l's) + sum_k hx*whh (64 k's)
            float ac0 = 0.f, ac1 = 0.f, ac2 = 0.f, ac3 = 0.f;
            {
                const u16* gp = G + (((size_t)t * LL + lg * 30) * 128 + span16) * 64 + b * 16 + lo;
#pragma unroll 6
                for (int i = 0; i < 30; i++){
                    short4 gv = *(const short4*)(gp + (size_t)i * 8192);
                    float al = als[b][lg * 30 + i];
                    ac0 = fmaf(al, bf2f((u16)gv.x), ac0);
                    ac1 = fmaf(al, bf2f((u16)gv.y), ac1);
                    ac2 = fmaf(al, bf2f((u16)gv.z), ac2);
                    ac3 = fmaf(al, bf2f((u16)gv.w), ac3);
                }
                const u16* wp = whh_p + (size_t)(lg * 64) * NJ + jj0 + jjl;
#pragma unroll 8
                for (int ki = 0; ki < 64; ki++){
                    short4 wv = *(const short4*)(wp + (size_t)ki * NJ);
                    float h = hxs[b][lg * 64 + ki];
                    ac0 = fmaf(h, bf2f((u16)wv.x), ac0);
                    ac1 = fmaf(h, bf2f((u16)wv.y), ac1);
                    ac2 = fmaf(h, bf2f((u16)wv.z), ac2);
                    ac3 = fmaf(h, bf2f((u16)wv.w), ac3);
                }
            }
            red[lg][b][jjl + 0] = ac0;
            red[lg][b][jjl + 1] = ac1;
            red[lg][b][jjl + 2] = ac2;
            red[lg][b][jjl + 3] = ac3;
            __syncthreads();
            if (tid < 128){
                int b2 = tid >> 5, jl = tid & 31;
                float v = 0.f;
#pragma unroll
                for (int q = 0; q < 8; q++) v += red[q][b2][jl];
                ast(&gbuf[(size_t)b2 * NJ + jj0 + jl], v);
            }
            __syncthreads();          // drains gbuf stores
            if (tid == 0)
                __hip_atomic_fetch_add(&ctr[(blk & 7) * 32], 1u, __ATOMIC_RELAXED, __HIP_MEMORY_SCOPE_AGENT);

            // prefetch G(t+1) (overlaps ready-wait)
            if (t < NT - 1){
                float sink = 0.f;
                if (tid < LL){
                    const u16* gp = G + (((size_t)(t + 1) * LL + tid) * 128 + 2 * s) * 64;
                    sink += (float)gp[0] + (float)gp[64];
                }
                asm volatile("" :: "v"(sink));
            }
        }
    }
}

// ---------------- MLP heads ----------------
__global__ __launch_bounds__(256) void mlp_kernel(
    const float* __restrict__ hseq,
    const float* __restrict__ sw1T, const float* __restrict__ sb1,
    const float* __restrict__ sw2,  const float* __restrict__ sb2,
    const float* __restrict__ sw3,  const float* __restrict__ sb3,
    const float* __restrict__ sw4,  const float* __restrict__ sb4,
    const float* __restrict__ vw1T, const float* __restrict__ vb1,
    const float* __restrict__ vw2,  const float* __restrict__ vb2,
    const float* __restrict__ vw3,  const float* __restrict__ vb3,
    const float* __restrict__ vw4,  const float* __restrict__ vb4,
    float* __restrict__ out)
{
    __shared__ float h0[HID];
    __shared__ float h1[2][100];
    __shared__ float h2[2][52];
    __shared__ float h3[2][12];
    int tb = blockIdx.x;
    int tid = threadIdx.x;
    for (int i = tid; i < HID; i += 256) h0[i] = hseq[(size_t)tb * HID + i];
    __syncthreads();
    if (tid < 100){
        float a = sb1[tid];
        for (int k = 0; k < HID; k++) a = fmaf(h0[k], sw1T[k*100 + tid], a);
        h1[0][tid] = fmaxf(a, 0.f);
    } else if (tid >= 128 && tid < 228){
        int u = tid - 128;
        float a = vb1[u];
        for (int k = 0; k < HID; k++) a = fmaf(h0[k], vw1T[k*100 + u], a);
        h1[1][u] = fmaxf(a, 0.f);
    }
    __syncthreads();
    if (tid < 50){
        float a = sb2[tid];
        for (int k = 0; k < 100; k++) a = fmaf(h1[0][k], sw2[tid*100 + k], a);
        h2[0][tid] = fmaxf(a, 0.f);
    } else if (tid >= 128 && tid < 178){
        int u = tid - 128;
        float a = vb2[u];
        for (int k = 0; k < 100; k++) a = fmaf(h1[1][k], vw2[u*100 + k], a);
        h2[1][u] = fmaxf(a, 0.f);
    }
    __syncthreads();
    if (tid < 10){
        float a = sb3[tid];
        for (int k = 0; k < 50; k++) a = fmaf(h2[0][k], sw3[tid*50 + k], a);
        h3[0][tid] = fmaxf(a, 0.f);
    } else if (tid >= 128 && tid < 138){
        int u = tid - 128;
        float a = vb3[u];
        for (int k = 0; k < 50; k++) a = fmaf(h2[1][k], vw3[u*50 + k], a);
        h3[1][u] = fmaxf(a, 0.f);
    }
    __syncthreads();
    if (tid == 0){
        float a = sb4[0];
        for (int k = 0; k < 10; k++) a = fmaf(h3[0][k], sw4[k], a);
        out[tb] = a;
    } else if (tid == 128){
        float a = vb4[0];
        for (int k = 0; k < 10; k++) a = fmaf(h3[1][k], vw4[k], a);
        out[360 + tb] = a;
    }
}

extern "C" void kernel_launch(void* const* d_in, const int* in_sizes, int n_in,
                              void* d_out, int out_size, void* d_ws, size_t ws_size,
                              hipStream_t stream)
{
    (void)in_sizes; (void)n_in; (void)out_size;
    if (ws_size < WS_NEEDED) return;

    const float* cam   = (const float*)d_in[0];
    const float* cw1   = (const float*)d_in[1];  const float* cb1 = (const float*)d_in[2];
    const float* cw2   = (const float*)d_in[3];  const float* cb2 = (const float*)d_in[4];
    const float* cw3   = (const float*)d_in[5];  const float* cb3 = (const float*)d_in[6];
    const float* cw4   = (const float*)d_in[7];  const float* cb4 = (const float*)d_in[8];
    const float* cw5   = (const float*)d_in[9];  const float* cb5 = (const float*)d_in[10];
    const float* pw    = (const float*)d_in[11]; const float* pb  = (const float*)d_in[12];
    const float* w_w   = (const float*)d_in[13]; const float* w_b = (const float*)d_in[14];
    const float* waw   = (const float*)d_in[15]; const float* wab = (const float*)d_in[16];
    const float* wih   = (const float*)d_in[17]; const float* whh = (const float*)d_in[18];
    const float* bih   = (const float*)d_in[19]; const float* bhh = (const float*)d_in[20];
    const float* sw1   = (const float*)d_in[21]; const float* sb1 = (const float*)d_in[22];
    const float* sw2   = (const float*)d_in[23]; const float* sb2 = (const float*)d_in[24];
    const float* sw3   = (const float*)d_in[25]; const float* sb3 = (const float*)d_in[26];
    const float* sw4   = (const float*)d_in[27]; const float* sb4 = (const float*)d_in[28];
    const float* vw1   = (const float*)d_in[29]; const float* vb1 = (const float*)d_in[30];
    const float* vw2   = (const float*)d_in[31]; const float* vb2 = (const float*)d_in[32];
    const float* vw3   = (const float*)d_in[33]; const float* vb3 = (const float*)d_in[34];
    const float* vw4   = (const float*)d_in[35]; const float* vb4 = (const float*)d_in[36];

    char* ws = (char*)d_ws;
    u16*   camcl = (u16*)(ws + CAMCL_OFF);
    u16*   a1    = (u16*)(ws + A1_OFF);
    u16*   a2    = (u16*)(ws + A2_OFF);
    u16*   a3    = (u16*)(ws + A3_OFF);
    u16*   a4    = (u16*)(ws + A4_OFF);
    u16*   a5    = (u16*)(ws + A5_OFF);
    u16*   w1b   = (u16*)(ws + W1B_OFF);
    u16*   w2b   = (u16*)(ws + W2B_OFF);
    u16*   w3b   = (u16*)(ws + W3B_OFF);
    u16*   w4b   = (u16*)(ws + W4B_OFF);
    u16*   w5b   = (u16*)(ws + W5B_OFF);
    float* feats = (float*)(ws + FEATS_OFF);
    float* proj  = (float*)(ws + PROJ_OFF);
    float* w_wT  = (float*)(ws + WWT_OFF);
    u16*   whh_p = (u16*)  (ws + WHHP_OFF);
    float* bsum  = (float*)(ws + BSUM_OFF);
    float* sw1T  = (float*)(ws + SW1T_OFF);
    float* vw1T  = (float*)(ws + VW1T_OFF);
    float* gbuf  = (float*)(ws + SC_GBUF);
    float* alpha = (float*)(ws + SC_ALPHA);
    float* hx_g  = (float*)(ws + SC_HX);
    unsigned int* ctr = (unsigned int*)(ws + SC_CTR);
    unsigned int* rdy = (unsigned int*)(ws + SC_RDY);
    float* hseq  = (float*)(ws + HSEQ_OFF);
    u16*   G     = (u16*)  (ws + G_OFF);

    cam_to_cl<<<(NIMG*96*160 + 255)/256, 256, 0, stream>>>(cam, camcl);
    prep_wbf<<<64, 256, 0, stream>>>(cw1, w1b, 24,  3,  8, 5, 28, 32);
    prep_wbf<<<64, 256, 0, stream>>>(cw2, w2b, 36, 24, 24, 5, 28, 48);
    prep_wbf<<<64, 256, 0, stream>>>(cw3, w3b, 48, 36, 40, 5, 28, 48);
    prep_wbf<<<64, 256, 0, stream>>>(cw4, w4b, 64, 48, 48, 3, 10, 64);
    prep_wbf<<<64, 256, 0, stream>>>(cw5, w5b, 64, 64, 64, 3,  9, 64);

    conv_mfma<   8,    32,   24,  24,   5,  28,   2, 2, 96, 160, 48, 80,  8, 40>
        <<<dim3(12, NIMG), 256, 0, stream>>>(camcl, w1b, cb1, a1);
    conv_mfma<  24,    48,   36,  40,   5,  28,   2, 2, 48,  80, 24, 40,  8, 20>
        <<<dim3(6, NIMG), 256, 0, stream>>>(a1, w2b, cb2, a2);
    conv_mfma<  40,    48,   48,  48,   5,  28,   2, 2, 24,  40, 12, 20, 12, 20>
        <<<dim3(1, NIMG), 256, 0, stream>>>(a2, w3b, cb3, a3);
    conv_mfma<  48,    64,   64,  64,   3,  10,   1, 1, 12,  20, 12, 20, 12, 20>
        <<<dim3(1, NIMG), 256, 0, stream>>>(a3, w4b, cb4, a4);
    conv_mfma<  64,    64,   64,  64,   3,   9,   1, 1, 12,  20, 12, 20, 12, 20>
        <<<dim3(1, NIMG), 256, 0, stream>>>(a4, w5b, cb5, a5);

    extract_feats<<<(NIMG*12*20*64 + 255)/256, 256, 0, stream>>>(a5, feats);
    proj_kernel<<<NIMG*LL/4, 256, 0, stream>>>(feats, pw, pb, proj);
    prep<<<1024, 256, 0, stream>>>(w_w, whh, bih, bhh, w_wT, whh_p, bsum);
    gcompute_mfma2<<<dim3(8, 240), 256, 0, stream>>>(feats, wih, G);

    // zero counters + ready line (re-zeroed every replay; epochs restart)
    hipMemsetAsync(ws + SC_CTR, 0, 2048, stream);

    scan_pc<<<TBLK, 256, 0, stream>>>(G, whh_p, bsum, proj, w_wT, w_b, waw, wab,
                                      gbuf, alpha, hx_g, ctr, rdy, hseq);

    prep2<<<256, 256, 0, stream>>>(sw1, vw1, sw1T, vw1T);

    mlp_kernel<<<360, 256, 0, stream>>>(hseq,
        sw1T, sb1, sw2, sb2, sw3, sb3, sw4, sb4,
        vw1T, vb1, vw2, vb2, vw3, vb3, vw4, vb4, (float*)d_out);
}

// Round 9
// 2001.836 us; speedup vs baseline: 1.9600x; 1.1222x over previous
//
#include <hip/hip_runtime.h>
#include <hip/hip_bf16.h>

typedef unsigned short u16;
using bf16x8 = __attribute__((ext_vector_type(8))) short;
using f32x4  = __attribute__((ext_vector_type(4))) float;

#define NB   4
#define NT   90
#define NIMG 360
#define LL   240
#define DD   64
#define HID  512
#define NJ   2048
#define GPB  16          // gates blocks per batch
#define TBLK (NB + NB*GPB) // 4 attn + 64 gates = 68

#define DEV __device__ __forceinline__

DEV float bf2f(u16 x){ unsigned int u = ((unsigned int)x) << 16; float f; __builtin_memcpy(&f, &u, 4); return f; }
DEV u16 f2bf(float f){ unsigned int u; __builtin_memcpy(&u, &f, 4); unsigned int r = (u + 0x7FFFu + ((u >> 16) & 1u)) >> 16; return (u16)r; }
DEV float sigm(float x){ return 1.f / (1.f + __expf(-x)); }
DEV float tanh_f(float x){ x = fminf(fmaxf(x, -15.f), 15.f); float e = __expf(2.f*x); return (e - 1.f) / (e + 1.f); }

// L3-coherent (agent-scope, relaxed) accessors for cross-XCD mutable state.
DEV void  ast(float* p, float v){ __hip_atomic_store(p, v, __ATOMIC_RELAXED, __HIP_MEMORY_SCOPE_AGENT); }
DEV float ald(const float* p){ return __hip_atomic_load(p, __ATOMIC_RELAXED, __HIP_MEMORY_SCOPE_AGENT); }
DEV void  astu(unsigned int* p, unsigned int v){ __hip_atomic_store(p, v, __ATOMIC_RELAXED, __HIP_MEMORY_SCOPE_AGENT); }
DEV unsigned int aldu(const unsigned int* p){ return __hip_atomic_load(p, __ATOMIC_RELAXED, __HIP_MEMORY_SCOPE_AGENT); }

// ---------------- workspace layout (bytes) ----------------
static const size_t G_OFF     = 0;            // u16 [90][240][128][64] (span-major) = 353,894,400 B
static const size_t CAMCL_OFF = 0;            // conv temporaries alias over G
static const size_t A1_OFF    = 88473600;
static const size_t A2_OFF    = 154828800;
static const size_t A3_OFF    = 182476800;
static const size_t A4_OFF    = 190771200;
static const size_t A5_OFF    = 201830400;
static const size_t W1B_OFF   = 212889600;
static const size_t W2B_OFF   = 212903936;
static const size_t W3B_OFF   = 212968448;
static const size_t W4B_OFF   = 213075968;
static const size_t W5B_OFF   = 213137408;
static const size_t FEATS_OFF = 353894400;    // fp32 [360][240][64]; dead during scan
static const size_t SC_ALPHA  = 353894400;    // fp32 [4][240] (4KB slot)
static const size_t SC_HX     = 353898496;    // fp32 [2][4][512] = 16KB (parity double-buffer)
static const size_t SC_CTR    = 353914880;    // u32 [4][32] = 512B (per-batch arrival counters)
static const size_t SC_RDY    = 353915392;    // u32 [4] in one 128B line
static const size_t PROJ_OFF  = 376012800;    // fp32 [360][240][64]
static const size_t WWT_OFF   = 398131200;    // fp32 [512][64]   w_w^T
static const size_t WHHP_OFF  = 398262272;    // bf16 [512][2048] whh^T, j-permuted
static const size_t BSUM_OFF  = 400359424;    // fp32 [2048] bih+bhh, j-permuted
static const size_t SW1T_OFF  = 400367616;    // fp32 [512][100]
static const size_t VW1T_OFF  = 400572416;    // fp32 [512][100]
static const size_t HSEQ_OFF  = 400809984;    // fp32 [90][4][512]
static const size_t WS_NEEDED = 401547264;

// ---------------- camera NCHW fp32 -> channels-last bf16 [n][h][w][8] ----------------
__global__ __launch_bounds__(256) void cam_to_cl(const float* __restrict__ cam, u16* __restrict__ out)
{
    int i = blockIdx.x * 256 + threadIdx.x;
    if (i >= NIMG * 96 * 160) return;
    int hw = i % (96 * 160);
    int n  = i / (96 * 160);
    const float* p = cam + (size_t)n * 3 * 96 * 160 + hw;
    bf16x8 v;
    v[0] = (short)f2bf(p[0]);
    v[1] = (short)f2bf(p[15360]);
    v[2] = (short)f2bf(p[30720]);
    v[3] = 0; v[4] = 0; v[5] = 0; v[6] = 0; v[7] = 0;
    *(bf16x8*)&out[(size_t)i * 8] = v;
}

// ---------------- weight prep for convs ----------------
__global__ __launch_bounds__(256) void prep_wbf(
    const float* __restrict__ w, u16* __restrict__ wbf,
    int COUT, int CIN, int CI_PAD, int KHW, int CELLS_PAD, int M_PAD)
{
    int K_PAD = CELLS_PAD * CI_PAD;
    int total = M_PAD * K_PAD;
    for (int i = blockIdx.x * 256 + threadIdx.x; i < total; i += gridDim.x * 256){
        int co = i / K_PAD, kk = i % K_PAD;
        int cell = kk / CI_PAD, ci = kk % CI_PAD;
        float v = 0.f;
        if (co < COUT && cell < KHW * KHW && ci < CIN){
            int kh = cell / KHW, kw = cell % KHW;
            v = w[((size_t)(co * CIN + ci) * KHW + kh) * KHW + kw];
        }
        wbf[i] = f2bf(v);
    }
}

// ---------------- implicit-GEMM MFMA conv (channels-last bf16 in/out) ----------------
template<int CI_PAD, int M_PAD, int COUT, int CO_STORE, int KHW, int CELLS_PAD,
         int S, int P, int HIN, int WIN, int HOUT, int WOUT, int TOH, int TOW>
__global__ __launch_bounds__(256) void conv_mfma(
    const u16* __restrict__ in, const u16* __restrict__ wbf,
    const float* __restrict__ bias, u16* __restrict__ out)
{
    constexpr int K_PAD = CELLS_PAD * CI_PAD;
    constexpr int CP8   = CI_PAD / 8;
    constexpr int TIH   = (TOH - 1) * S + KHW;
    constexpr int TIW   = (TOW - 1) * S + KHW;
    constexpr int TIW_H = (TIW + 1) / 2;
    constexpr int NF    = TOH * TOW / 16;
    constexpr int NK0   = K_PAD / 32;
    constexpr int MF    = M_PAD / 16;
    constexpr int NPW   = (NF + 3) / 4;
    constexpr int LDSE  = (S == 2) ? TIH * CP8 * 2 * TIW_H * 8 : TIH * CP8 * TIW * 8;
    static_assert((TOH * TOW) % 16 == 0, "N tile");
    static_assert(K_PAD % 32 == 0, "K pad");

    __shared__ u16 lds[LDSE];

    int tile = blockIdx.x, n = blockIdx.y;
    constexpr int TW_T = WOUT / TOW;
    int th = tile / TW_T, tw = tile % TW_T;
    int oh0 = th * TOH, ow0 = tw * TOW;
    int ih0 = oh0 * S - P, iw0 = ow0 * S - P;
    int tid = threadIdx.x;

    constexpr int CHUNKS = TIH * TIW * CP8;
    for (int i = tid; i < CHUNKS; i += 256){
        int c8 = i % CP8; int r2 = i / CP8;
        int iw = r2 % TIW, ih = r2 / TIW;
        int ihg = ih0 + ih, iwg = iw0 + iw;
        bf16x8 v = {0,0,0,0,0,0,0,0};
        if (ihg >= 0 && ihg < HIN && iwg >= 0 && iwg < WIN)
            v = *(const bf16x8*)&in[(((size_t)n * HIN + ihg) * WIN + iwg) * CI_PAD + c8 * 8];
        int off;
        if (S == 2) off = (((ih * CP8 + c8) * 2 + (iw & 1)) * TIW_H + (iw >> 1)) * 8;
        else        off = ((ih * CP8 + c8) * TIW + iw) * 8;
        *(bf16x8*)&lds[off] = v;
    }
    __syncthreads();

    int lane = tid & 63, wv = tid >> 6;
    int col = lane & 15, grp = lane >> 4;

    int ihb[NPW], iwb[NPW];
    bool act[NPW];
#pragma unroll
    for (int i2 = 0; i2 < NPW; i2++){
        int nf = wv + i2 * 4;
        act[i2] = (nf < NF);
        int nfc = act[i2] ? nf : 0;
        int nsp = nfc * 16 + col;
        ihb[i2] = (nsp / TOW) * S;
        iwb[i2] = (nsp % TOW) * S;
    }

    f32x4 acc[MF][NPW];
#pragma unroll
    for (int mf = 0; mf < MF; mf++)
#pragma unroll
        for (int i2 = 0; i2 < NPW; i2++)
            acc[mf][i2] = (f32x4){0.f, 0.f, 0.f, 0.f};

    for (int k0 = 0; k0 < NK0; k0++){
        bf16x8 a[MF];
#pragma unroll
        for (int mf = 0; mf < MF; mf++)
            a[mf] = *(const bf16x8*)&wbf[(size_t)(mf * 16 + col) * K_PAD + k0 * 32 + grp * 8];
        int k8 = k0 * 32 + grp * 8;
        int cell = k8 / CI_PAD;
        int ci0  = k8 - cell * CI_PAD;
        if (cell >= KHW * KHW) cell = 0;
        int kh = cell / KHW, kw = cell - (cell / KHW) * KHW;
        int cb = ci0 >> 3;
#pragma unroll
        for (int i2 = 0; i2 < NPW; i2++){
            if (!act[i2]) continue;
            int ih = ihb[i2] + kh;
            int off;
            if (S == 2) off = (((ih * CP8 + cb) * 2 + (kw & 1)) * TIW_H + (iwb[i2] >> 1) + (kw >> 1)) * 8;
            else        off = ((ih * CP8 + cb) * TIW + iwb[i2] + kw) * 8;
            bf16x8 b = *(const bf16x8*)&lds[off];
#pragma unroll
            for (int mf = 0; mf < MF; mf++)
                acc[mf][i2] = __builtin_amdgcn_mfma_f32_16x16x32_bf16(a[mf], b, acc[mf][i2], 0, 0, 0);
        }
    }

#pragma unroll
    for (int i2 = 0; i2 < NPW; i2++){
        if (!act[i2]) continue;
        int nf = wv + i2 * 4;
        int nsp = nf * 16 + col;
        int oh = oh0 + nsp / TOW, ow = ow0 + nsp % TOW;
        size_t obase = (((size_t)n * HOUT + oh) * WOUT + ow) * CO_STORE;
#pragma unroll
        for (int mf = 0; mf < MF; mf++){
            int cobase = mf * 16 + grp * 4;
#pragma unroll
            for (int r = 0; r < 4; r++){
                int co = cobase + r;
                if (co < CO_STORE){
                    float x = (co < COUT) ? fmaxf(acc[mf][i2][r] + bias[co], 0.f) : 0.f;
                    out[obase + co] = f2bf(x);
                }
            }
        }
    }
}

// ---------------- feats rearrange ----------------
__global__ __launch_bounds__(256) void extract_feats(const u16* __restrict__ a5, float* __restrict__ feats)
{
    int idx = blockIdx.x * 256 + threadIdx.x;
    if (idx >= NIMG * 12 * 20 * 64) return;
    int c = idx & 63; int t1 = idx >> 6;
    int w = t1 % 20; t1 /= 20;
    int h = t1 % 12; int n = t1 / 12;
    float v = bf2f(a5[idx]);
    int flat = w * 768 + c * 12 + h;
    int d = flat / 240, l = flat % 240;
    feats[((size_t)n * LL + l) * DD + d] = v;
}

// ---------------- proj = feats @ proj_w.T + proj_b ----------------
__global__ __launch_bounds__(256) void proj_kernel(
    const float* __restrict__ feats, const float* __restrict__ pw,
    const float* __restrict__ pb, float* __restrict__ proj)
{
    __shared__ float pws[64][65];
    __shared__ float fs[4][64];
    int tid = threadIdx.x;
    size_t R0 = (size_t)blockIdx.x * 4;
    for (int i = tid; i < 4096; i += 256){
        int dd = i / 64, d = i % 64;
        pws[d][dd] = pw[dd*64 + d];
    }
    { int r = tid / 64, d = tid % 64; fs[r][d] = feats[(R0 + r)*64 + d]; }
    __syncthreads();
    int r = tid / 64, dd = tid % 64;
    float a = pb[dd];
    for (int d = 0; d < 64; d++) a = fmaf(fs[r][d], pws[d][dd], a);
    proj[(R0 + r)*64 + dd] = a;
}

// ---------------- prep: whh permute, bias combine, w_w transpose ----------------
__global__ __launch_bounds__(256) void prep(
    const float* __restrict__ w_w, const float* __restrict__ whh,
    const float* __restrict__ bih, const float* __restrict__ bhh,
    float* __restrict__ w_wT, u16* __restrict__ whh_p, float* __restrict__ bsum)
{
    int idx = blockIdx.x * 256 + threadIdx.x;
    int stride = gridDim.x * 256;
    for (int i = idx; i < 512*64; i += stride){
        int k = i / 64, dd = i % 64;
        w_wT[i] = w_w[dd*512 + k];
    }
    for (int i = idx; i < 512*2048; i += stride){
        int k = i / 2048, jj = i % 2048;
        int u = jj >> 2, g = jj & 3, j = g*512 + u;
        whh_p[i] = f2bf(whh[(size_t)j*512 + k]);
    }
    for (int i = idx; i < 2048; i += stride){
        int u = i >> 2, g = i & 3, j = g*512 + u;
        bsum[i] = bih[j] + bhh[j];
    }
}

// ---------------- prep2: MLP first-layer transposes ----------------
__global__ __launch_bounds__(256) void prep2(
    const float* __restrict__ sw1, const float* __restrict__ vw1,
    float* __restrict__ sw1T, float* __restrict__ vw1T)
{
    int idx = blockIdx.x * 256 + threadIdx.x;
    int stride = gridDim.x * 256;
    for (int i = idx; i < 512*100; i += stride){
        int k = i / 100, u = i % 100;
        sw1T[i] = sw1[u*512 + k];
        vw1T[i] = vw1[u*512 + k];
    }
}

// ---------------- gcompute via MFMA (G span-major: [((t*240+l)*128+s)*64 + b*16 + lo]) --------
__global__ __launch_bounds__(256, 2) void gcompute_mfma2(
    const float* __restrict__ feats, const float* __restrict__ wih, u16* __restrict__ G)
{
    __shared__ u16 Bsw[256 * 64];
    __shared__ u16 Asw[128 * 64];
    float (*obuf)[1024] = (float(*)[1024])Asw;

    int jt = blockIdx.x, l = blockIdx.y;
    int j0 = jt * 256;
    int tid = threadIdx.x;
    int g8 = tid & 7;

    for (int p = 0; p < 8; p++){
        int row = p * 32 + (tid >> 3);
        int jj = j0 + row;
        int j = (jj & 3) * 512 + (jj >> 2);
        const float* src = wih + (size_t)j * 15360 + l * 64 + g8 * 8;
        float4 v0 = *(const float4*)src;
        float4 v1 = *(const float4*)(src + 4);
        bf16x8 pk;
        pk[0]=(short)f2bf(v0.x); pk[1]=(short)f2bf(v0.y); pk[2]=(short)f2bf(v0.z); pk[3]=(short)f2bf(v0.w);
        pk[4]=(short)f2bf(v1.x); pk[5]=(short)f2bf(v1.y); pk[6]=(short)f2bf(v1.z); pk[7]=(short)f2bf(v1.w);
        *(bf16x8*)&Bsw[(row * 8 + (g8 ^ (row & 7))) * 8] = pk;
    }
    __syncthreads();

    int lane = tid & 63, w = tid >> 6;
    int col = lane & 15, grp = lane >> 4;

    bf16x8 bfr[2][4];
#pragma unroll
    for (int k0 = 0; k0 < 2; k0++)
#pragma unroll
        for (int nf = 0; nf < 4; nf++){
            int row = w * 64 + nf * 16 + col;
            bfr[k0][nf] = *(const bf16x8*)&Bsw[(row * 8 + ((k0 * 4 + grp) ^ (row & 7))) * 8];
        }

    for (int mt = 0; mt < 3; mt++){
        int m0 = mt * 128;
        __syncthreads();
        for (int p = 0; p < 4; p++){
            int row = p * 32 + (tid >> 3);
            const float* src = feats + ((size_t)(m0 + row) * LL + l) * DD + g8 * 8;
            float4 v0 = *(const float4*)src;
            float4 v1 = *(const float4*)(src + 4);
            bf16x8 pk;
            pk[0]=(short)f2bf(v0.x); pk[1]=(short)f2bf(v0.y); pk[2]=(short)f2bf(v0.z); pk[3]=(short)f2bf(v0.w);
            pk[4]=(short)f2bf(v1.x); pk[5]=(short)f2bf(v1.y); pk[6]=(short)f2bf(v1.z); pk[7]=(short)f2bf(v1.w);
            *(bf16x8*)&Asw[(row * 8 + (g8 ^ (row & 7))) * 8] = pk;
        }
        __syncthreads();

        f32x4 acc[8][4];
#pragma unroll
        for (int mf = 0; mf < 8; mf++)
#pragma unroll
            for (int nf = 0; nf < 4; nf++) acc[mf][nf] = (f32x4){0.f,0.f,0.f,0.f};

#pragma unroll
        for (int k0 = 0; k0 < 2; k0++){
#pragma unroll
            for (int mf = 0; mf < 8; mf++){
                int row = mf * 16 + col;
                bf16x8 a = *(const bf16x8*)&Asw[(row * 8 + ((k0 * 4 + grp) ^ (row & 7))) * 8];
#pragma unroll
                for (int nf = 0; nf < 4; nf++)
                    acc[mf][nf] = __builtin_amdgcn_mfma_f32_16x16x32_bf16(a, bfr[k0][nf], acc[mf][nf], 0, 0, 0);
            }
        }
        __syncthreads();

#pragma unroll
        for (int mf = 0; mf < 8; mf++){
#pragma unroll
            for (int nf = 0; nf < 4; nf++)
#pragma unroll
                for (int r = 0; r < 4; r++)
                    obuf[w][(grp * 4 + r) * 64 + nf * 16 + col] = acc[mf][nf][r];
#pragma unroll
            for (int p = 0; p < 2; p++){
                int rloc = p * 8 + (lane >> 3);
                int c0 = (lane & 7) * 8;
                float4 r0 = *(const float4*)&obuf[w][rloc * 64 + c0];
                float4 r1 = *(const float4*)&obuf[w][rloc * 64 + c0 + 4];
                int m = m0 + mf * 16 + rloc;
                if (m < NIMG){
                    int b = m / NT, tt = m % NT;
                    int jj8 = j0 + w * 64 + c0;
                    int s = jj8 >> 4, lo = jj8 & 15;
                    bf16x8 pk;
                    pk[0]=(short)f2bf(r0.x); pk[1]=(short)f2bf(r0.y); pk[2]=(short)f2bf(r0.z); pk[3]=(short)f2bf(r0.w);
                    pk[4]=(short)f2bf(r1.x); pk[5]=(short)f2bf(r1.y); pk[6]=(short)f2bf(r1.z); pk[7]=(short)f2bf(r1.w);
                    *(bf16x8*)&G[((((size_t)tt * LL + l) * 128 + s) * 64) + b * 16 + lo] = pk;
                }
            }
        }
    }
}

// ---------------- persistent batch-partitioned scan (4 x [1 attn + 16 gates]) ----------------
// blk 0-3: attn block for batch blk. blk 4..67: gates block idx=blk-4, b=idx&3, g=idx>>2.
// Gates block (b,g): owns jj in [g*128,(g+1)*128) = units [g*32,(g+1)*32) of batch b;
//   computes G-weighted sum + whh term, does LSTM pointwise locally (cx in LDS),
//   publishes 32-float h-slice to hx parity buffer + increments ctr[b].
// Attn block b: waits ctr[b]==16(t+1), stages h(t), computes alpha(t+1) (proj in LDS),
//   publishes alpha + rdy[b]=t+2.
__global__ __launch_bounds__(256) void scan_pc(
    const u16* __restrict__ G, const u16* __restrict__ whh_p,
    const float* __restrict__ bsum, const float* __restrict__ proj,
    const float* __restrict__ w_wT, const float* __restrict__ w_b,
    const float* __restrict__ waw, const float* __restrict__ wab,
    float* __restrict__ alpha_g, float* __restrict__ hx_g,
    unsigned int* __restrict__ ctr, unsigned int* __restrict__ rdy,
    float* __restrict__ hseq)
{
    int tid = threadIdx.x, blk = blockIdx.x;

    if (blk < NB){
        // ================= ATTN BLOCK (batch b) =================
        __shared__ float projL[LL * DD];   // 60KB
        __shared__ float hloc[HID];        // 2KB
        __shared__ float apjs[DD];         // 256B
        __shared__ float scr[256];         // 1KB (red2 during gemv, esl during softmax)
        int b = blk;
        float wb0 = wab[0];

        // init: stage proj(0), alpha(0) with hx=0, rdy=1
        {
            const float* src = proj + ((size_t)(b * NT + 0)) * LL * DD;
            for (int it = 0; it < 15; it++){
                int idx = it * 256 + tid;
                *(float4*)&projL[idx * 4] = *(const float4*)&src[idx * 4];
            }
        }
        if (tid < DD) apjs[tid] = w_b[tid];
        __syncthreads();
        if (tid < LL){
            const float* pr = &projL[tid * DD];
            float e = 0.f;
#pragma unroll
            for (int d = 0; d < DD; d++) e = fmaf(tanh_f(pr[d] + apjs[d]), waw[d], e);
            scr[tid] = e + wb0;
        }
        __syncthreads();
        if (tid < 64){
            float m = -1e30f;
            for (int l = tid; l < LL; l += 64) m = fmaxf(m, scr[l]);
#pragma unroll
            for (int off = 32; off; off >>= 1) m = fmaxf(m, __shfl_xor(m, off));
            float ex[4]; int c = 0; float ssum = 0.f;
            for (int l = tid; l < LL; l += 64){ float e2 = __expf(scr[l] - m); ex[c++] = e2; ssum += e2; }
#pragma unroll
            for (int off = 32; off; off >>= 1) ssum += __shfl_xor(ssum, off);
            float inv = 1.f / ssum; c = 0;
            for (int l = tid; l < LL; l += 64) ast(&alpha_g[b * LL + l], ex[c++] * inv);
        }
        __syncthreads();
        if (tid == 0) astu(&rdy[b], 1u);

        for (int t = 0; t < NT - 1; t++){
            // stage proj(t+1) (overlaps gates phase)
            {
                const float* src = proj + ((size_t)(b * NT + t + 1)) * LL * DD;
                for (int it = 0; it < 15; it++){
                    int idx = it * 256 + tid;
                    *(float4*)&projL[idx * 4] = *(const float4*)&src[idx * 4];
                }
            }
            // wait all 16 gates blocks of this batch
            if (tid == 0){
                unsigned int tgt = 16u * (t + 1);
                int g = 0;
                while (aldu(&ctr[b * 32]) < tgt){
                    if (++g > (1 << 24)) break;
                    __builtin_amdgcn_s_sleep(1);
                }
            }
            __syncthreads();

            // stage h(t) from parity buffer
            {
                const float* hsrc = hx_g + (size_t)((t + 1) & 1) * (NB * HID) + b * HID;
                hloc[tid] = ald(&hsrc[tid]);
                hloc[tid + 256] = ald(&hsrc[tid + 256]);
            }
            __syncthreads();

            // apj gemv (4-way k split)
            {
                int dd = tid & 63, dq = tid >> 6;
                float p = 0.f;
                for (int ki = 0; ki < 128; ki++){
                    int k = dq * 128 + ki;
                    p = fmaf(hloc[k], w_wT[k * 64 + dd], p);
                }
                scr[dq * 64 + dd] = p;
            }
            __syncthreads();
            if (tid < 64) apjs[tid] = w_b[tid] + scr[tid] + scr[64 + tid] + scr[128 + tid] + scr[192 + tid];
            __syncthreads();
            // es + softmax
            float ev = 0.f;
            if (tid < LL){
                const float* pr = &projL[tid * DD];
#pragma unroll
                for (int d = 0; d < DD; d++) ev = fmaf(tanh_f(pr[d] + apjs[d]), waw[d], ev);
                ev += wb0;
            }
            __syncthreads();   // scr free (apjs consumed)
            if (tid < LL) scr[tid] = ev;
            __syncthreads();
            if (tid < 64){
                float m = -1e30f;
                for (int l = tid; l < LL; l += 64) m = fmaxf(m, scr[l]);
#pragma unroll
                for (int off = 32; off; off >>= 1) m = fmaxf(m, __shfl_xor(m, off));
                float ex[4]; int c = 0; float ssum = 0.f;
                for (int l = tid; l < LL; l += 64){ float e2 = __expf(scr[l] - m); ex[c++] = e2; ssum += e2; }
#pragma unroll
                for (int off = 32; off; off >>= 1) ssum += __shfl_xor(ssum, off);
                float inv = 1.f / ssum; c = 0;
                for (int l = tid; l < LL; l += 64) ast(&alpha_g[b * LL + l], ex[c++] * inv);
            }
            __syncthreads();   // drains alpha stores
            if (tid == 0) astu(&rdy[b], (unsigned int)(t + 2));
        }
    } else {
        // ================= GATES BLOCK (batch b, group g) =================
        __shared__ float als[LL];        // 960B
        __shared__ float hxs[HID];       // 2KB
        __shared__ float red[8][128];    // 4KB
        __shared__ float gat[128];       // 512B
        __shared__ float cxl[32];        // 128B
        int idx = blk - NB;
        int b = idx & 3, g = idx >> 2;
        int jq = tid & 31, lg = tid >> 5;       // 32 jj-quads x 8 l/k-groups
        int jjg = g * 128 + jq * 4;             // first of 4 jj
        int span16 = jjg >> 4, lo16 = jjg & 15;

        if (tid < 32) cxl[tid] = 0.f;

        // prefetch G(0) slice into own-XCD L2 (same addressing as compute)
        {
            float sink = 0.f;
            const u16* gp = G + ((size_t)(0 * LL + lg * 30) * 128 + span16) * 64 + b * 16 + lo16;
            for (int i = 0; i < 30; i++){
                short4 gv = *(const short4*)(gp + (size_t)i * 8192);
                sink += (float)gv.x;
            }
            asm volatile("" :: "v"(sink));
        }

        for (int t = 0; t < NT; t++){
            // wait alpha(t) ready
            if (tid == 0){
                int gu = 0;
                while (aldu(&rdy[b]) < (unsigned int)(t + 1)){
                    if (++gu > (1 << 24)) break;
                    __builtin_amdgcn_s_sleep(1);
                }
            }
            __syncthreads();

            // stage alpha(t) + h(t-1)
            if (tid < LL) als[tid] = ald(&alpha_g[b * LL + tid]);
            {
                const float* hsrc = hx_g + (size_t)(t & 1) * (NB * HID) + b * HID;
                hxs[tid] = ald(&hsrc[tid]);
                hxs[tid + 256] = ald(&hsrc[tid + 256]);
            }
            __syncthreads();

            // gates partial: sum_l alpha*G (30 l) + sum_k hx*whh (64 k)
            float ac0 = 0.f, ac1 = 0.f, ac2 = 0.f, ac3 = 0.f;
            {
                const u16* gp = G + (((size_t)t * LL + lg * 30) * 128 + span16) * 64 + b * 16 + lo16;
#pragma unroll 6
                for (int i = 0; i < 30; i++){
                    short4 gv = *(const short4*)(gp + (size_t)i * 8192);
                    float al = als[lg * 30 + i];
                    ac0 = fmaf(al, bf2f((u16)gv.x), ac0);
                    ac1 = fmaf(al, bf2f((u16)gv.y), ac1);
                    ac2 = fmaf(al, bf2f((u16)gv.z), ac2);
                    ac3 = fmaf(al, bf2f((u16)gv.w), ac3);
                }
                const u16* wp = whh_p + (size_t)(lg * 64) * NJ + jjg;
#pragma unroll 8
                for (int ki = 0; ki < 64; ki++){
                    short4 wv = *(const short4*)(wp + (size_t)ki * NJ);
                    float h = hxs[lg * 64 + ki];
                    ac0 = fmaf(h, bf2f((u16)wv.x), ac0);
                    ac1 = fmaf(h, bf2f((u16)wv.y), ac1);
                    ac2 = fmaf(h, bf2f((u16)wv.z), ac2);
                    ac3 = fmaf(h, bf2f((u16)wv.w), ac3);
                }
            }
            red[lg][jq * 4 + 0] = ac0;
            red[lg][jq * 4 + 1] = ac1;
            red[lg][jq * 4 + 2] = ac2;
            red[lg][jq * 4 + 3] = ac3;
            __syncthreads();
            if (tid < 128){
                float v = 0.f;
#pragma unroll
                for (int q = 0; q < 8; q++) v += red[q][tid];
                gat[tid] = v;
            }
            __syncthreads();

            // local pointwise cell for units [g*32, g*32+32)
            if (tid < 32){
                int jjb = g * 128 + tid * 4;
                float4 bs = *(const float4*)&bsum[jjb];
                float gi = gat[tid*4 + 0] + bs.x;
                float gf = gat[tid*4 + 1] + bs.y;
                float gg = gat[tid*4 + 2] + bs.z;
                float go = gat[tid*4 + 3] + bs.w;
                float c = sigm(gf) * cxl[tid] + sigm(gi) * tanhf(gg);
                cxl[tid] = c;
                float h = sigm(go) * tanhf(c);
                int u = g * 32 + tid;
                ast(&hx_g[(size_t)((t + 1) & 1) * (NB * HID) + b * HID + u], h);
                hseq[((size_t)t * NB + b) * HID + u] = h;
            }
            __syncthreads();          // drains h stores (vmcnt 0 before barrier)
            if (tid == 0)
                __hip_atomic_fetch_add(&ctr[b * 32], 1u, __ATOMIC_RELAXED, __HIP_MEMORY_SCOPE_AGENT);

            // prefetch G(t+1) slice (overlaps next rdy-wait)
            if (t < NT - 1){
                float sink = 0.f;
                const u16* gp = G + (((size_t)(t + 1) * LL + lg * 30) * 128 + span16) * 64 + b * 16 + lo16;
                for (int i = 0; i < 30; i++){
                    short4 gv = *(const short4*)(gp + (size_t)i * 8192);
                    sink += (float)gv.x;
                }
                asm volatile("" :: "v"(sink));
            }
        }
    }
}

// ---------------- MLP heads ----------------
__global__ __launch_bounds__(256) void mlp_kernel(
    const float* __restrict__ hseq,
    const float* __restrict__ sw1T, const float* __restrict__ sb1,
    const float* __restrict__ sw2,  const float* __restrict__ sb2,
    const float* __restrict__ sw3,  const float* __restrict__ sb3,
    const float* __restrict__ sw4,  const float* __restrict__ sb4,
    const float* __restrict__ vw1T, const float* __restrict__ vb1,
    const float* __restrict__ vw2,  const float* __restrict__ vb2,
    const float* __restrict__ vw3,  const float* __restrict__ vb3,
    const float* __restrict__ vw4,  const float* __restrict__ vb4,
    float* __restrict__ out)
{
    __shared__ float h0[HID];
    __shared__ float h1[2][100];
    __shared__ float h2[2][52];
    __shared__ float h3[2][12];
    int tb = blockIdx.x;
    int tid = threadIdx.x;
    for (int i = tid; i < HID; i += 256) h0[i] = hseq[(size_t)tb * HID + i];
    __syncthreads();
    if (tid < 100){
        float a = sb1[tid];
        for (int k = 0; k < HID; k++) a = fmaf(h0[k], sw1T[k*100 + tid], a);
        h1[0][tid] = fmaxf(a, 0.f);
    } else if (tid >= 128 && tid < 228){
        int u = tid - 128;
        float a = vb1[u];
        for (int k = 0; k < HID; k++) a = fmaf(h0[k], vw1T[k*100 + u], a);
        h1[1][u] = fmaxf(a, 0.f);
    }
    __syncthreads();
    if (tid < 50){
        float a = sb2[tid];
        for (int k = 0; k < 100; k++) a = fmaf(h1[0][k], sw2[tid*100 + k], a);
        h2[0][tid] = fmaxf(a, 0.f);
    } else if (tid >= 128 && tid < 178){
        int u = tid - 128;
        float a = vb2[u];
        for (int k = 0; k < 100; k++) a = fmaf(h1[1][k], vw2[u*100 + k], a);
        h2[1][u] = fmaxf(a, 0.f);
    }
    __syncthreads();
    if (tid < 10){
        float a = sb3[tid];
        for (int k = 0; k < 50; k++) a = fmaf(h2[0][k], sw3[tid*50 + k], a);
        h3[0][tid] = fmaxf(a, 0.f);
    } else if (tid >= 128 && tid < 138){
        int u = tid - 128;
        float a = vb3[u];
        for (int k = 0; k < 50; k++) a = fmaf(h2[1][k], vw3[u*50 + k], a);
        h3[1][u] = fmaxf(a, 0.f);
    }
    __syncthreads();
    if (tid == 0){
        float a = sb4[0];
        for (int k = 0; k < 10; k++) a = fmaf(h3[0][k], sw4[k], a);
        out[tb] = a;
    } else if (tid == 128){
        float a = vb4[0];
        for (int k = 0; k < 10; k++) a = fmaf(h3[1][k], vw4[k], a);
        out[360 + tb] = a;
    }
}

extern "C" void kernel_launch(void* const* d_in, const int* in_sizes, int n_in,
                              void* d_out, int out_size, void* d_ws, size_t ws_size,
                              hipStream_t stream)
{
    (void)in_sizes; (void)n_in; (void)out_size;
    if (ws_size < WS_NEEDED) return;

    const float* cam   = (const float*)d_in[0];
    const float* cw1   = (const float*)d_in[1];  const float* cb1 = (const float*)d_in[2];
    const float* cw2   = (const float*)d_in[3];  const float* cb2 = (const float*)d_in[4];
    const float* cw3   = (const float*)d_in[5];  const float* cb3 = (const float*)d_in[6];
    const float* cw4   = (const float*)d_in[7];  const float* cb4 = (const float*)d_in[8];
    const float* cw5   = (const float*)d_in[9];  const float* cb5 = (const float*)d_in[10];
    const float* pw    = (const float*)d_in[11]; const float* pb  = (const float*)d_in[12];
    const float* w_w   = (const float*)d_in[13]; const float* w_b = (const float*)d_in[14];
    const float* waw   = (const float*)d_in[15]; const float* wab = (const float*)d_in[16];
    const float* wih   = (const float*)d_in[17]; const float* whh = (const float*)d_in[18];
    const float* bih   = (const float*)d_in[19]; const float* bhh = (const float*)d_in[20];
    const float* sw1   = (const float*)d_in[21]; const float* sb1 = (const float*)d_in[22];
    const float* sw2   = (const float*)d_in[23]; const float* sb2 = (const float*)d_in[24];
    const float* sw3   = (const float*)d_in[25]; const float* sb3 = (const float*)d_in[26];
    const float* sw4   = (const float*)d_in[27]; const float* sb4 = (const float*)d_in[28];
    const float* vw1   = (const float*)d_in[29]; const float* vb1 = (const float*)d_in[30];
    const float* vw2   = (const float*)d_in[31]; const float* vb2 = (const float*)d_in[32];
    const float* vw3   = (const float*)d_in[33]; const float* vb3 = (const float*)d_in[34];
    const float* vw4   = (const float*)d_in[35]; const float* vb4 = (const float*)d_in[36];

    char* ws = (char*)d_ws;
    u16*   camcl = (u16*)(ws + CAMCL_OFF);
    u16*   a1    = (u16*)(ws + A1_OFF);
    u16*   a2    = (u16*)(ws + A2_OFF);
    u16*   a3    = (u16*)(ws + A3_OFF);
    u16*   a4    = (u16*)(ws + A4_OFF);
    u16*   a5    = (u16*)(ws + A5_OFF);
    u16*   w1b   = (u16*)(ws + W1B_OFF);
    u16*   w2b   = (u16*)(ws + W2B_OFF);
    u16*   w3b   = (u16*)(ws + W3B_OFF);
    u16*   w4b   = (u16*)(ws + W4B_OFF);
    u16*   w5b   = (u16*)(ws + W5B_OFF);
    float* feats = (float*)(ws + FEATS_OFF);
    float* proj  = (float*)(ws + PROJ_OFF);
    float* w_wT  = (float*)(ws + WWT_OFF);
    u16*   whh_p = (u16*)  (ws + WHHP_OFF);
    float* bsum  = (float*)(ws + BSUM_OFF);
    float* sw1T  = (float*)(ws + SW1T_OFF);
    float* vw1T  = (float*)(ws + VW1T_OFF);
    float* alpha = (float*)(ws + SC_ALPHA);
    float* hx_g  = (float*)(ws + SC_HX);
    unsigned int* ctr = (unsigned int*)(ws + SC_CTR);
    unsigned int* rdy = (unsigned int*)(ws + SC_RDY);
    float* hseq  = (float*)(ws + HSEQ_OFF);
    u16*   G     = (u16*)  (ws + G_OFF);

    cam_to_cl<<<(NIMG*96*160 + 255)/256, 256, 0, stream>>>(cam, camcl);
    prep_wbf<<<64, 256, 0, stream>>>(cw1, w1b, 24,  3,  8, 5, 28, 32);
    prep_wbf<<<64, 256, 0, stream>>>(cw2, w2b, 36, 24, 24, 5, 28, 48);
    prep_wbf<<<64, 256, 0, stream>>>(cw3, w3b, 48, 36, 40, 5, 28, 48);
    prep_wbf<<<64, 256, 0, stream>>>(cw4, w4b, 64, 48, 48, 3, 10, 64);
    prep_wbf<<<64, 256, 0, stream>>>(cw5, w5b, 64, 64, 64, 3,  9, 64);

    conv_mfma<   8,    32,   24,  24,   5,  28,   2, 2, 96, 160, 48, 80,  8, 40>
        <<<dim3(12, NIMG), 256, 0, stream>>>(camcl, w1b, cb1, a1);
    conv_mfma<  24,    48,   36,  40,   5,  28,   2, 2, 48,  80, 24, 40,  8, 20>
        <<<dim3(6, NIMG), 256, 0, stream>>>(a1, w2b, cb2, a2);
    conv_mfma<  40,    48,   48,  48,   5,  28,   2, 2, 24,  40, 12, 20, 12, 20>
        <<<dim3(1, NIMG), 256, 0, stream>>>(a2, w3b, cb3, a3);
    conv_mfma<  48,    64,   64,  64,   3,  10,   1, 1, 12,  20, 12, 20, 12, 20>
        <<<dim3(1, NIMG), 256, 0, stream>>>(a3, w4b, cb4, a4);
    conv_mfma<  64,    64,   64,  64,   3,   9,   1, 1, 12,  20, 12, 20, 12, 20>
        <<<dim3(1, NIMG), 256, 0, stream>>>(a4, w5b, cb5, a5);

    extract_feats<<<(NIMG*12*20*64 + 255)/256, 256, 0, stream>>>(a5, feats);
    proj_kernel<<<NIMG*LL/4, 256, 0, stream>>>(feats, pw, pb, proj);
    prep<<<1024, 256, 0, stream>>>(w_w, whh, bih, bhh, w_wT, whh_p, bsum);
    gcompute_mfma2<<<dim3(8, 240), 256, 0, stream>>>(feats, wih, G);

    // zero scan state: alpha(4KB) + hx both parity buffers(16KB) + ctr(512B) + rdy(128B)
    hipMemsetAsync(ws + SC_ALPHA, 0, 21120, stream);

    scan_pc<<<TBLK, 256, 0, stream>>>(G, whh_p, bsum, proj, w_wT, w_b, waw, wab,
                                      alpha, hx_g, ctr, rdy, hseq);

    prep2<<<256, 256, 0, stream>>>(sw1, vw1, sw1T, vw1T);

    mlp_kernel<<<360, 256, 0, stream>>>(hseq,
        sw1T, sb1, sw2, sb2, sw3, sb3, sw4, sb4,
        vw1T, vb1, vw2, vb2, vw3, vb3, vw4, vb4, (float*)d_out);
}

// Round 10
// 1608.109 us; speedup vs baseline: 2.4399x; 1.2448x over previous
//
#include <hip/hip_runtime.h>
#include <hip/hip_bf16.h>

typedef unsigned short u16;
using bf16x8 = __attribute__((ext_vector_type(8))) short;
using f32x4  = __attribute__((ext_vector_type(4))) float;

#define NB   4
#define NT   90
#define NIMG 360
#define LL   240
#define DD   64
#define HID  512
#define NJ   2048
#define GPB  16          // gates blocks per batch
#define TBLK (NB + NB*GPB) // 4 attn + 64 gates = 68

#define DEV __device__ __forceinline__

DEV float bf2f(u16 x){ unsigned int u = ((unsigned int)x) << 16; float f; __builtin_memcpy(&f, &u, 4); return f; }
DEV u16 f2bf(float f){ unsigned int u; __builtin_memcpy(&u, &f, 4); unsigned int r = (u + 0x7FFFu + ((u >> 16) & 1u)) >> 16; return (u16)r; }
DEV float sigm(float x){ return 1.f / (1.f + __expf(-x)); }
DEV float tanh_f(float x){ x = fminf(fmaxf(x, -15.f), 15.f); float e = __expf(2.f*x); return (e - 1.f) / (e + 1.f); }

// L3-coherent (agent-scope, relaxed) accessors for cross-XCD mutable state.
DEV void  ast(float* p, float v){ __hip_atomic_store(p, v, __ATOMIC_RELAXED, __HIP_MEMORY_SCOPE_AGENT); }
DEV float ald(const float* p){ return __hip_atomic_load(p, __ATOMIC_RELAXED, __HIP_MEMORY_SCOPE_AGENT); }
DEV void  astu(unsigned int* p, unsigned int v){ __hip_atomic_store(p, v, __ATOMIC_RELAXED, __HIP_MEMORY_SCOPE_AGENT); }
DEV unsigned int aldu(const unsigned int* p){ return __hip_atomic_load(p, __ATOMIC_RELAXED, __HIP_MEMORY_SCOPE_AGENT); }

// ---------------- workspace layout (bytes) ----------------
// G2 layout: [b][g(16)][t(90)][l(240)][128 jj] u16 — block (b,g) slice at step t is one
// contiguous 61,440B run: (((b*16+g)*90 + t)*240*128 + l*128 + jjl)
static const size_t G_OFF     = 0;            // 353,894,400 B
static const size_t CAMCL_OFF = 0;            // conv temporaries alias over G
static const size_t A1_OFF    = 88473600;
static const size_t A2_OFF    = 154828800;
static const size_t A3_OFF    = 182476800;
static const size_t A4_OFF    = 190771200;
static const size_t A5_OFF    = 201830400;
static const size_t W1B_OFF   = 212889600;
static const size_t W2B_OFF   = 212903936;
static const size_t W3B_OFF   = 212968448;
static const size_t W4B_OFF   = 213075968;
static const size_t W5B_OFF   = 213137408;
static const size_t FEATS_OFF = 353894400;    // fp32 [360][240][64]; dead during scan
static const size_t SC_ALPHA  = 353894400;    // fp32 [4][240] (4KB slot)
static const size_t SC_HX     = 353898496;    // fp32 [2][4][512] = 16KB (parity double-buffer)
static const size_t SC_CTR    = 353914880;    // u32 [4][32] = 512B (per-batch arrival counters)
static const size_t SC_RDY    = 353915392;    // u32 [4] in one 128B line
static const size_t PROJ_OFF  = 376012800;    // fp32 [360][240][64]
static const size_t WWT_OFF   = 398131200;    // fp32 [512][64]   w_w^T
static const size_t WHHP_OFF  = 398262272;    // bf16 [512][2048] whh^T, j-permuted
static const size_t BSUM_OFF  = 400359424;    // fp32 [2048] bih+bhh, j-permuted
static const size_t SW1T_OFF  = 400367616;    // fp32 [512][100]
static const size_t VW1T_OFF  = 400572416;    // fp32 [512][100]
static const size_t HSEQ_OFF  = 400809984;    // fp32 [90][4][512]
static const size_t WS_NEEDED = 401547264;

// ---------------- camera NCHW fp32 -> channels-last bf16 [n][h][w][8] ----------------
__global__ __launch_bounds__(256) void cam_to_cl(const float* __restrict__ cam, u16* __restrict__ out)
{
    int i = blockIdx.x * 256 + threadIdx.x;
    if (i >= NIMG * 96 * 160) return;
    int hw = i % (96 * 160);
    int n  = i / (96 * 160);
    const float* p = cam + (size_t)n * 3 * 96 * 160 + hw;
    bf16x8 v;
    v[0] = (short)f2bf(p[0]);
    v[1] = (short)f2bf(p[15360]);
    v[2] = (short)f2bf(p[30720]);
    v[3] = 0; v[4] = 0; v[5] = 0; v[6] = 0; v[7] = 0;
    *(bf16x8*)&out[(size_t)i * 8] = v;
}

// ---------------- weight prep for convs ----------------
__global__ __launch_bounds__(256) void prep_wbf(
    const float* __restrict__ w, u16* __restrict__ wbf,
    int COUT, int CIN, int CI_PAD, int KHW, int CELLS_PAD, int M_PAD)
{
    int K_PAD = CELLS_PAD * CI_PAD;
    int total = M_PAD * K_PAD;
    for (int i = blockIdx.x * 256 + threadIdx.x; i < total; i += gridDim.x * 256){
        int co = i / K_PAD, kk = i % K_PAD;
        int cell = kk / CI_PAD, ci = kk % CI_PAD;
        float v = 0.f;
        if (co < COUT && cell < KHW * KHW && ci < CIN){
            int kh = cell / KHW, kw = cell % KHW;
            v = w[((size_t)(co * CIN + ci) * KHW + kh) * KHW + kw];
        }
        wbf[i] = f2bf(v);
    }
}

// ---------------- implicit-GEMM MFMA conv (channels-last bf16 in/out) ----------------
template<int CI_PAD, int M_PAD, int COUT, int CO_STORE, int KHW, int CELLS_PAD,
         int S, int P, int HIN, int WIN, int HOUT, int WOUT, int TOH, int TOW>
__global__ __launch_bounds__(256) void conv_mfma(
    const u16* __restrict__ in, const u16* __restrict__ wbf,
    const float* __restrict__ bias, u16* __restrict__ out)
{
    constexpr int K_PAD = CELLS_PAD * CI_PAD;
    constexpr int CP8   = CI_PAD / 8;
    constexpr int TIH   = (TOH - 1) * S + KHW;
    constexpr int TIW   = (TOW - 1) * S + KHW;
    constexpr int TIW_H = (TIW + 1) / 2;
    constexpr int NF    = TOH * TOW / 16;
    constexpr int NK0   = K_PAD / 32;
    constexpr int MF    = M_PAD / 16;
    constexpr int NPW   = (NF + 3) / 4;
    constexpr int LDSE  = (S == 2) ? TIH * CP8 * 2 * TIW_H * 8 : TIH * CP8 * TIW * 8;
    static_assert((TOH * TOW) % 16 == 0, "N tile");
    static_assert(K_PAD % 32 == 0, "K pad");

    __shared__ u16 lds[LDSE];

    int tile = blockIdx.x, n = blockIdx.y;
    constexpr int TW_T = WOUT / TOW;
    int th = tile / TW_T, tw = tile % TW_T;
    int oh0 = th * TOH, ow0 = tw * TOW;
    int ih0 = oh0 * S - P, iw0 = ow0 * S - P;
    int tid = threadIdx.x;

    constexpr int CHUNKS = TIH * TIW * CP8;
    for (int i = tid; i < CHUNKS; i += 256){
        int c8 = i % CP8; int r2 = i / CP8;
        int iw = r2 % TIW, ih = r2 / TIW;
        int ihg = ih0 + ih, iwg = iw0 + iw;
        bf16x8 v = {0,0,0,0,0,0,0,0};
        if (ihg >= 0 && ihg < HIN && iwg >= 0 && iwg < WIN)
            v = *(const bf16x8*)&in[(((size_t)n * HIN + ihg) * WIN + iwg) * CI_PAD + c8 * 8];
        int off;
        if (S == 2) off = (((ih * CP8 + c8) * 2 + (iw & 1)) * TIW_H + (iw >> 1)) * 8;
        else        off = ((ih * CP8 + c8) * TIW + iw) * 8;
        *(bf16x8*)&lds[off] = v;
    }
    __syncthreads();

    int lane = tid & 63, wv = tid >> 6;
    int col = lane & 15, grp = lane >> 4;

    int ihb[NPW], iwb[NPW];
    bool act[NPW];
#pragma unroll
    for (int i2 = 0; i2 < NPW; i2++){
        int nf = wv + i2 * 4;
        act[i2] = (nf < NF);
        int nfc = act[i2] ? nf : 0;
        int nsp = nfc * 16 + col;
        ihb[i2] = (nsp / TOW) * S;
        iwb[i2] = (nsp % TOW) * S;
    }

    f32x4 acc[MF][NPW];
#pragma unroll
    for (int mf = 0; mf < MF; mf++)
#pragma unroll
        for (int i2 = 0; i2 < NPW; i2++)
            acc[mf][i2] = (f32x4){0.f, 0.f, 0.f, 0.f};

    for (int k0 = 0; k0 < NK0; k0++){
        bf16x8 a[MF];
#pragma unroll
        for (int mf = 0; mf < MF; mf++)
            a[mf] = *(const bf16x8*)&wbf[(size_t)(mf * 16 + col) * K_PAD + k0 * 32 + grp * 8];
        int k8 = k0 * 32 + grp * 8;
        int cell = k8 / CI_PAD;
        int ci0  = k8 - cell * CI_PAD;
        if (cell >= KHW * KHW) cell = 0;
        int kh = cell / KHW, kw = cell - (cell / KHW) * KHW;
        int cb = ci0 >> 3;
#pragma unroll
        for (int i2 = 0; i2 < NPW; i2++){
            if (!act[i2]) continue;
            int ih = ihb[i2] + kh;
            int off;
            if (S == 2) off = (((ih * CP8 + cb) * 2 + (kw & 1)) * TIW_H + (iwb[i2] >> 1) + (kw >> 1)) * 8;
            else        off = ((ih * CP8 + cb) * TIW + iwb[i2] + kw) * 8;
            bf16x8 b = *(const bf16x8*)&lds[off];
#pragma unroll
            for (int mf = 0; mf < MF; mf++)
                acc[mf][i2] = __builtin_amdgcn_mfma_f32_16x16x32_bf16(a[mf], b, acc[mf][i2], 0, 0, 0);
        }
    }

#pragma unroll
    for (int i2 = 0; i2 < NPW; i2++){
        if (!act[i2]) continue;
        int nf = wv + i2 * 4;
        int nsp = nf * 16 + col;
        int oh = oh0 + nsp / TOW, ow = ow0 + nsp % TOW;
        size_t obase = (((size_t)n * HOUT + oh) * WOUT + ow) * CO_STORE;
#pragma unroll
        for (int mf = 0; mf < MF; mf++){
            int cobase = mf * 16 + grp * 4;
#pragma unroll
            for (int r = 0; r < 4; r++){
                int co = cobase + r;
                if (co < CO_STORE){
                    float x = (co < COUT) ? fmaxf(acc[mf][i2][r] + bias[co], 0.f) : 0.f;
                    out[obase + co] = f2bf(x);
                }
            }
        }
    }
}

// ---------------- feats rearrange ----------------
__global__ __launch_bounds__(256) void extract_feats(const u16* __restrict__ a5, float* __restrict__ feats)
{
    int idx = blockIdx.x * 256 + threadIdx.x;
    if (idx >= NIMG * 12 * 20 * 64) return;
    int c = idx & 63; int t1 = idx >> 6;
    int w = t1 % 20; t1 /= 20;
    int h = t1 % 12; int n = t1 / 12;
    float v = bf2f(a5[idx]);
    int flat = w * 768 + c * 12 + h;
    int d = flat / 240, l = flat % 240;
    feats[((size_t)n * LL + l) * DD + d] = v;
}

// ---------------- proj = feats @ proj_w.T + proj_b ----------------
__global__ __launch_bounds__(256) void proj_kernel(
    const float* __restrict__ feats, const float* __restrict__ pw,
    const float* __restrict__ pb, float* __restrict__ proj)
{
    __shared__ float pws[64][65];
    __shared__ float fs[4][64];
    int tid = threadIdx.x;
    size_t R0 = (size_t)blockIdx.x * 4;
    for (int i = tid; i < 4096; i += 256){
        int dd = i / 64, d = i % 64;
        pws[d][dd] = pw[dd*64 + d];
    }
    { int r = tid / 64, d = tid % 64; fs[r][d] = feats[(R0 + r)*64 + d]; }
    __syncthreads();
    int r = tid / 64, dd = tid % 64;
    float a = pb[dd];
    for (int d = 0; d < 64; d++) a = fmaf(fs[r][d], pws[d][dd], a);
    proj[(R0 + r)*64 + dd] = a;
}

// ---------------- prep: whh permute, bias combine, w_w transpose ----------------
__global__ __launch_bounds__(256) void prep(
    const float* __restrict__ w_w, const float* __restrict__ whh,
    const float* __restrict__ bih, const float* __restrict__ bhh,
    float* __restrict__ w_wT, u16* __restrict__ whh_p, float* __restrict__ bsum)
{
    int idx = blockIdx.x * 256 + threadIdx.x;
    int stride = gridDim.x * 256;
    for (int i = idx; i < 512*64; i += stride){
        int k = i / 64, dd = i % 64;
        w_wT[i] = w_w[dd*512 + k];
    }
    for (int i = idx; i < 512*2048; i += stride){
        int k = i / 2048, jj = i % 2048;
        int u = jj >> 2, g = jj & 3, j = g*512 + u;
        whh_p[i] = f2bf(whh[(size_t)j*512 + k]);
    }
    for (int i = idx; i < 2048; i += stride){
        int u = i >> 2, g = i & 3, j = g*512 + u;
        bsum[i] = bih[j] + bhh[j];
    }
}

// ---------------- prep2: MLP first-layer transposes ----------------
__global__ __launch_bounds__(256) void prep2(
    const float* __restrict__ sw1, const float* __restrict__ vw1,
    float* __restrict__ sw1T, float* __restrict__ vw1T)
{
    int idx = blockIdx.x * 256 + threadIdx.x;
    int stride = gridDim.x * 256;
    for (int i = idx; i < 512*100; i += stride){
        int k = i / 100, u = i % 100;
        sw1T[i] = sw1[u*512 + k];
        vw1T[i] = vw1[u*512 + k];
    }
}

// ---------------- gcompute via MFMA; G2 slice-contiguous layout ----------------
__global__ __launch_bounds__(256, 2) void gcompute_mfma2(
    const float* __restrict__ feats, const float* __restrict__ wih, u16* __restrict__ G)
{
    __shared__ u16 Bsw[256 * 64];
    __shared__ u16 Asw[128 * 64];
    float (*obuf)[1024] = (float(*)[1024])Asw;

    int jt = blockIdx.x, l = blockIdx.y;
    int j0 = jt * 256;
    int tid = threadIdx.x;
    int g8 = tid & 7;

    for (int p = 0; p < 8; p++){
        int row = p * 32 + (tid >> 3);
        int jj = j0 + row;
        int j = (jj & 3) * 512 + (jj >> 2);
        const float* src = wih + (size_t)j * 15360 + l * 64 + g8 * 8;
        float4 v0 = *(const float4*)src;
        float4 v1 = *(const float4*)(src + 4);
        bf16x8 pk;
        pk[0]=(short)f2bf(v0.x); pk[1]=(short)f2bf(v0.y); pk[2]=(short)f2bf(v0.z); pk[3]=(short)f2bf(v0.w);
        pk[4]=(short)f2bf(v1.x); pk[5]=(short)f2bf(v1.y); pk[6]=(short)f2bf(v1.z); pk[7]=(short)f2bf(v1.w);
        *(bf16x8*)&Bsw[(row * 8 + (g8 ^ (row & 7))) * 8] = pk;
    }
    __syncthreads();

    int lane = tid & 63, w = tid >> 6;
    int col = lane & 15, grp = lane >> 4;

    bf16x8 bfr[2][4];
#pragma unroll
    for (int k0 = 0; k0 < 2; k0++)
#pragma unroll
        for (int nf = 0; nf < 4; nf++){
            int row = w * 64 + nf * 16 + col;
            bfr[k0][nf] = *(const bf16x8*)&Bsw[(row * 8 + ((k0 * 4 + grp) ^ (row & 7))) * 8];
        }

    for (int mt = 0; mt < 3; mt++){
        int m0 = mt * 128;
        __syncthreads();
        for (int p = 0; p < 4; p++){
            int row = p * 32 + (tid >> 3);
            const float* src = feats + ((size_t)(m0 + row) * LL + l) * DD + g8 * 8;
            float4 v0 = *(const float4*)src;
            float4 v1 = *(const float4*)(src + 4);
            bf16x8 pk;
            pk[0]=(short)f2bf(v0.x); pk[1]=(short)f2bf(v0.y); pk[2]=(short)f2bf(v0.z); pk[3]=(short)f2bf(v0.w);
            pk[4]=(short)f2bf(v1.x); pk[5]=(short)f2bf(v1.y); pk[6]=(short)f2bf(v1.z); pk[7]=(short)f2bf(v1.w);
            *(bf16x8*)&Asw[(row * 8 + (g8 ^ (row & 7))) * 8] = pk;
        }
        __syncthreads();

        f32x4 acc[8][4];
#pragma unroll
        for (int mf = 0; mf < 8; mf++)
#pragma unroll
            for (int nf = 0; nf < 4; nf++) acc[mf][nf] = (f32x4){0.f,0.f,0.f,0.f};

#pragma unroll
        for (int k0 = 0; k0 < 2; k0++){
#pragma unroll
            for (int mf = 0; mf < 8; mf++){
                int row = mf * 16 + col;
                bf16x8 a = *(const bf16x8*)&Asw[(row * 8 + ((k0 * 4 + grp) ^ (row & 7))) * 8];
#pragma unroll
                for (int nf = 0; nf < 4; nf++)
                    acc[mf][nf] = __builtin_amdgcn_mfma_f32_16x16x32_bf16(a, bfr[k0][nf], acc[mf][nf], 0, 0, 0);
            }
        }
        __syncthreads();

#pragma unroll
        for (int mf = 0; mf < 8; mf++){
#pragma unroll
            for (int nf = 0; nf < 4; nf++)
#pragma unroll
                for (int r = 0; r < 4; r++)
                    obuf[w][(grp * 4 + r) * 64 + nf * 16 + col] = acc[mf][nf][r];
#pragma unroll
            for (int p = 0; p < 2; p++){
                int rloc = p * 8 + (lane >> 3);
                int c0 = (lane & 7) * 8;
                float4 r0 = *(const float4*)&obuf[w][rloc * 64 + c0];
                float4 r1 = *(const float4*)&obuf[w][rloc * 64 + c0 + 4];
                int m = m0 + mf * 16 + rloc;
                if (m < NIMG){
                    int b = m / NT, tt = m % NT;
                    int jj8 = j0 + w * 64 + c0;
                    int gg2 = jj8 >> 7, jjl = jj8 & 127;
                    bf16x8 pk;
                    pk[0]=(short)f2bf(r0.x); pk[1]=(short)f2bf(r0.y); pk[2]=(short)f2bf(r0.z); pk[3]=(short)f2bf(r0.w);
                    pk[4]=(short)f2bf(r1.x); pk[5]=(short)f2bf(r1.y); pk[6]=(short)f2bf(r1.z); pk[7]=(short)f2bf(r1.w);
                    *(bf16x8*)&G[(((size_t)(b * GPB + gg2) * NT + tt) * LL + l) * 128 + jjl] = pk;
                }
            }
        }
    }
}

// ---------------- persistent batch-partitioned scan (4 x [1 attn + 16 gates]) ----------------
__global__ __launch_bounds__(256) void scan_pc(
    const u16* __restrict__ G, const u16* __restrict__ whh_p,
    const float* __restrict__ bsum, const float* __restrict__ proj,
    const float* __restrict__ w_wT, const float* __restrict__ w_b,
    const float* __restrict__ waw, const float* __restrict__ wab,
    float* __restrict__ alpha_g, float* __restrict__ hx_g,
    unsigned int* __restrict__ ctr, unsigned int* __restrict__ rdy,
    float* __restrict__ hseq)
{
    int tid = threadIdx.x, blk = blockIdx.x;

    if (blk < NB){
        // ================= ATTN BLOCK (batch b) =================
        __shared__ float projL[LL * DD];   // 60KB
        __shared__ float hloc[HID];        // 2KB
        __shared__ float apjs[DD];         // 256B
        __shared__ float scr[256];         // 1KB
        int b = blk;
        float wb0 = wab[0];

        {
            const float* src = proj + ((size_t)(b * NT + 0)) * LL * DD;
            for (int it = 0; it < 15; it++){
                int idx = it * 256 + tid;
                *(float4*)&projL[idx * 4] = *(const float4*)&src[idx * 4];
            }
        }
        if (tid < DD) apjs[tid] = w_b[tid];
        __syncthreads();
        if (tid < LL){
            const float* pr = &projL[tid * DD];
            float e = 0.f;
#pragma unroll
            for (int d = 0; d < DD; d++) e = fmaf(tanh_f(pr[d] + apjs[d]), waw[d], e);
            scr[tid] = e + wb0;
        }
        __syncthreads();
        if (tid < 64){
            float m = -1e30f;
            for (int l = tid; l < LL; l += 64) m = fmaxf(m, scr[l]);
#pragma unroll
            for (int off = 32; off; off >>= 1) m = fmaxf(m, __shfl_xor(m, off));
            float ex[4]; int c = 0; float ssum = 0.f;
            for (int l = tid; l < LL; l += 64){ float e2 = __expf(scr[l] - m); ex[c++] = e2; ssum += e2; }
#pragma unroll
            for (int off = 32; off; off >>= 1) ssum += __shfl_xor(ssum, off);
            float inv = 1.f / ssum; c = 0;
            for (int l = tid; l < LL; l += 64) ast(&alpha_g[b * LL + l], ex[c++] * inv);
        }
        __syncthreads();
        if (tid == 0) astu(&rdy[b], 1u);

        for (int t = 0; t < NT - 1; t++){
            {
                const float* src = proj + ((size_t)(b * NT + t + 1)) * LL * DD;
                for (int it = 0; it < 15; it++){
                    int idx = it * 256 + tid;
                    *(float4*)&projL[idx * 4] = *(const float4*)&src[idx * 4];
                }
            }
            if (tid == 0){
                unsigned int tgt = 16u * (t + 1);
                int g = 0;
                while (aldu(&ctr[b * 32]) < tgt){
                    if (++g > (1 << 24)) break;
                    __builtin_amdgcn_s_sleep(1);
                }
            }
            __syncthreads();

            {
                const float* hsrc = hx_g + (size_t)((t + 1) & 1) * (NB * HID) + b * HID;
                hloc[tid] = ald(&hsrc[tid]);
                hloc[tid + 256] = ald(&hsrc[tid + 256]);
            }
            __syncthreads();

            {
                int dd = tid & 63, dq = tid >> 6;
                float p = 0.f;
                for (int ki = 0; ki < 128; ki++){
                    int k = dq * 128 + ki;
                    p = fmaf(hloc[k], w_wT[k * 64 + dd], p);
                }
                scr[dq * 64 + dd] = p;
            }
            __syncthreads();
            if (tid < 64) apjs[tid] = w_b[tid] + scr[tid] + scr[64 + tid] + scr[128 + tid] + scr[192 + tid];
            __syncthreads();
            float ev = 0.f;
            if (tid < LL){
                const float* pr = &projL[tid * DD];
#pragma unroll
                for (int d = 0; d < DD; d++) ev = fmaf(tanh_f(pr[d] + apjs[d]), waw[d], ev);
                ev += wb0;
            }
            __syncthreads();
            if (tid < LL) scr[tid] = ev;
            __syncthreads();
            if (tid < 64){
                float m = -1e30f;
                for (int l = tid; l < LL; l += 64) m = fmaxf(m, scr[l]);
#pragma unroll
                for (int off = 32; off; off >>= 1) m = fmaxf(m, __shfl_xor(m, off));
                float ex[4]; int c = 0; float ssum = 0.f;
                for (int l = tid; l < LL; l += 64){ float e2 = __expf(scr[l] - m); ex[c++] = e2; ssum += e2; }
#pragma unroll
                for (int off = 32; off; off >>= 1) ssum += __shfl_xor(ssum, off);
                float inv = 1.f / ssum; c = 0;
                for (int l = tid; l < LL; l += 64) ast(&alpha_g[b * LL + l], ex[c++] * inv);
            }
            __syncthreads();
            if (tid == 0) astu(&rdy[b], (unsigned int)(t + 2));
        }
    } else {
        // ================= GATES BLOCK (batch b, group g) =================
        __shared__ float als[LL];        // 960B
        __shared__ float hxs[HID];       // 2KB
        __shared__ float red[8][128];    // 4KB
        __shared__ float gat[128];       // 512B
        __shared__ float cxl[32];        // 128B
        int idx = blk - NB;
        int b = idx & 3, g = idx >> 2;
        int jq = tid & 31, lg = tid >> 5;       // 32 jj-quads x 8 l/k-groups
        // G2 slice base for (b,g,t): (((b*16+g)*90 + t)*240*128 elements, contiguous 61,440B
        const size_t SLICE = (size_t)LL * 128;
        const u16* gbase0 = G + ((size_t)(b * GPB + g) * NT) * SLICE;

        if (tid < 32) cxl[tid] = 0.f;

        // prefetch G(0) slice: coalesced float4 over the contiguous 61KB run
        {
            float sink = 0.f;
            const float4* pp = (const float4*)(gbase0);
#pragma unroll
            for (int i = 0; i < 15; i++){
                float4 v = pp[i * 256 + tid];
                sink += v.x + v.w;
            }
            asm volatile("" :: "v"(sink));
        }

        for (int t = 0; t < NT; t++){
            if (tid == 0){
                int gu = 0;
                while (aldu(&rdy[b]) < (unsigned int)(t + 1)){
                    if (++gu > (1 << 24)) break;
                    __builtin_amdgcn_s_sleep(1);
                }
            }
            __syncthreads();

            if (tid < LL) als[tid] = ald(&alpha_g[b * LL + tid]);
            {
                const float* hsrc = hx_g + (size_t)(t & 1) * (NB * HID) + b * HID;
                hxs[tid] = ald(&hsrc[tid]);
                hxs[tid + 256] = ald(&hsrc[tid + 256]);
            }
            __syncthreads();

            // gates partial: sum_l alpha*G (30 l, L2-hot contiguous) + sum_k hx*whh (64 k)
            float ac0 = 0.f, ac1 = 0.f, ac2 = 0.f, ac3 = 0.f;
            {
                const u16* gp = gbase0 + (size_t)t * SLICE + (size_t)(lg * 30) * 128 + jq * 4;
#pragma unroll 6
                for (int i = 0; i < 30; i++){
                    short4 gv = *(const short4*)(gp + i * 128);
                    float al = als[lg * 30 + i];
                    ac0 = fmaf(al, bf2f((u16)gv.x), ac0);
                    ac1 = fmaf(al, bf2f((u16)gv.y), ac1);
                    ac2 = fmaf(al, bf2f((u16)gv.z), ac2);
                    ac3 = fmaf(al, bf2f((u16)gv.w), ac3);
                }
                const u16* wp = whh_p + (size_t)(lg * 64) * NJ + g * 128 + jq * 4;
#pragma unroll 8
                for (int ki = 0; ki < 64; ki++){
                    short4 wv = *(const short4*)(wp + (size_t)ki * NJ);
                    float h = hxs[lg * 64 + ki];
                    ac0 = fmaf(h, bf2f((u16)wv.x), ac0);
                    ac1 = fmaf(h, bf2f((u16)wv.y), ac1);
                    ac2 = fmaf(h, bf2f((u16)wv.z), ac2);
                    ac3 = fmaf(h, bf2f((u16)wv.w), ac3);
                }
            }
            red[lg][jq * 4 + 0] = ac0;
            red[lg][jq * 4 + 1] = ac1;
            red[lg][jq * 4 + 2] = ac2;
            red[lg][jq * 4 + 3] = ac3;
            __syncthreads();
            if (tid < 128){
                float v = 0.f;
#pragma unroll
                for (int q = 0; q < 8; q++) v += red[q][tid];
                gat[tid] = v;
            }
            __syncthreads();

            if (tid < 32){
                int jjb = g * 128 + tid * 4;
                float4 bs = *(const float4*)&bsum[jjb];
                float gi = gat[tid*4 + 0] + bs.x;
                float gf = gat[tid*4 + 1] + bs.y;
                float gg = gat[tid*4 + 2] + bs.z;
                float go = gat[tid*4 + 3] + bs.w;
                float c = sigm(gf) * cxl[tid] + sigm(gi) * tanhf(gg);
                cxl[tid] = c;
                float h = sigm(go) * tanhf(c);
                int u = g * 32 + tid;
                ast(&hx_g[(size_t)((t + 1) & 1) * (NB * HID) + b * HID + u], h);
                hseq[((size_t)t * NB + b) * HID + u] = h;
            }
            __syncthreads();
            if (tid == 0)
                __hip_atomic_fetch_add(&ctr[b * 32], 1u, __ATOMIC_RELAXED, __HIP_MEMORY_SCOPE_AGENT);

            // prefetch G(t+1) slice (contiguous, coalesced; overlaps next rdy-wait)
            if (t < NT - 1){
                float sink = 0.f;
                const float4* pp = (const float4*)(gbase0 + (size_t)(t + 1) * SLICE);
#pragma unroll
                for (int i = 0; i < 15; i++){
                    float4 v = pp[i * 256 + tid];
                    sink += v.x + v.w;
                }
                asm volatile("" :: "v"(sink));
            }
        }
    }
}

// ---------------- MLP heads ----------------
__global__ __launch_bounds__(256) void mlp_kernel(
    const float* __restrict__ hseq,
    const float* __restrict__ sw1T, const float* __restrict__ sb1,
    const float* __restrict__ sw2,  const float* __restrict__ sb2,
    const float* __restrict__ sw3,  const float* __restrict__ sb3,
    const float* __restrict__ sw4,  const float* __restrict__ sb4,
    const float* __restrict__ vw1T, const float* __restrict__ vb1,
    const float* __restrict__ vw2,  const float* __restrict__ vb2,
    const float* __restrict__ vw3,  const float* __restrict__ vb3,
    const float* __restrict__ vw4,  const float* __restrict__ vb4,
    float* __restrict__ out)
{
    __shared__ float h0[HID];
    __shared__ float h1[2][100];
    __shared__ float h2[2][52];
    __shared__ float h3[2][12];
    int tb = blockIdx.x;
    int tid = threadIdx.x;
    for (int i = tid; i < HID; i += 256) h0[i] = hseq[(size_t)tb * HID + i];
    __syncthreads();
    if (tid < 100){
        float a = sb1[tid];
        for (int k = 0; k < HID; k++) a = fmaf(h0[k], sw1T[k*100 + tid], a);
        h1[0][tid] = fmaxf(a, 0.f);
    } else if (tid >= 128 && tid < 228){
        int u = tid - 128;
        float a = vb1[u];
        for (int k = 0; k < HID; k++) a = fmaf(h0[k], vw1T[k*100 + u], a);
        h1[1][u] = fmaxf(a, 0.f);
    }
    __syncthreads();
    if (tid < 50){
        float a = sb2[tid];
        for (int k = 0; k < 100; k++) a = fmaf(h1[0][k], sw2[tid*100 + k], a);
        h2[0][tid] = fmaxf(a, 0.f);
    } else if (tid >= 128 && tid < 178){
        int u = tid - 128;
        float a = vb2[u];
        for (int k = 0; k < 100; k++) a = fmaf(h1[1][k], vw2[u*100 + k], a);
        h2[1][u] = fmaxf(a, 0.f);
    }
    __syncthreads();
    if (tid < 10){
        float a = sb3[tid];
        for (int k = 0; k < 50; k++) a = fmaf(h2[0][k], sw3[tid*50 + k], a);
        h3[0][tid] = fmaxf(a, 0.f);
    } else if (tid >= 128 && tid < 138){
        int u = tid - 128;
        float a = vb3[u];
        for (int k = 0; k < 50; k++) a = fmaf(h2[1][k], vw3[u*50 + k], a);
        h3[1][u] = fmaxf(a, 0.f);
    }
    __syncthreads();
    if (tid == 0){
        float a = sb4[0];
        for (int k = 0; k < 10; k++) a = fmaf(h3[0][k], sw4[k], a);
        out[tb] = a;
    } else if (tid == 128){
        float a = vb4[0];
        for (int k = 0; k < 10; k++) a = fmaf(h3[1][k], vw4[k], a);
        out[360 + tb] = a;
    }
}

extern "C" void kernel_launch(void* const* d_in, const int* in_sizes, int n_in,
                              void* d_out, int out_size, void* d_ws, size_t ws_size,
                              hipStream_t stream)
{
    (void)in_sizes; (void)n_in; (void)out_size;
    if (ws_size < WS_NEEDED) return;

    const float* cam   = (const float*)d_in[0];
    const float* cw1   = (const float*)d_in[1];  const float* cb1 = (const float*)d_in[2];
    const float* cw2   = (const float*)d_in[3];  const float* cb2 = (const float*)d_in[4];
    const float* cw3   = (const float*)d_in[5];  const float* cb3 = (const float*)d_in[6];
    const float* cw4   = (const float*)d_in[7];  const float* cb4 = (const float*)d_in[8];
    const float* cw5   = (const float*)d_in[9];  const float* cb5 = (const float*)d_in[10];
    const float* pw    = (const float*)d_in[11]; const float* pb  = (const float*)d_in[12];
    const float* w_w   = (const float*)d_in[13]; const float* w_b = (const float*)d_in[14];
    const float* waw   = (const float*)d_in[15]; const float* wab = (const float*)d_in[16];
    const float* wih   = (const float*)d_in[17]; const float* whh = (const float*)d_in[18];
    const float* bih   = (const float*)d_in[19]; const float* bhh = (const float*)d_in[20];
    const float* sw1   = (const float*)d_in[21]; const float* sb1 = (const float*)d_in[22];
    const float* sw2   = (const float*)d_in[23]; const float* sb2 = (const float*)d_in[24];
    const float* sw3   = (const float*)d_in[25]; const float* sb3 = (const float*)d_in[26];
    const float* sw4   = (const float*)d_in[27]; const float* sb4 = (const float*)d_in[28];
    const float* vw1   = (const float*)d_in[29]; const float* vb1 = (const float*)d_in[30];
    const float* vw2   = (const float*)d_in[31]; const float* vb2 = (const float*)d_in[32];
    const float* vw3   = (const float*)d_in[33]; const float* vb3 = (const float*)d_in[34];
    const float* vw4   = (const float*)d_in[35]; const float* vb4 = (const float*)d_in[36];

    char* ws = (char*)d_ws;
    u16*   camcl = (u16*)(ws + CAMCL_OFF);
    u16*   a1    = (u16*)(ws + A1_OFF);
    u16*   a2    = (u16*)(ws + A2_OFF);
    u16*   a3    = (u16*)(ws + A3_OFF);
    u16*   a4    = (u16*)(ws + A4_OFF);
    u16*   a5    = (u16*)(ws + A5_OFF);
    u16*   w1b   = (u16*)(ws + W1B_OFF);
    u16*   w2b   = (u16*)(ws + W2B_OFF);
    u16*   w3b   = (u16*)(ws + W3B_OFF);
    u16*   w4b   = (u16*)(ws + W4B_OFF);
    u16*   w5b   = (u16*)(ws + W5B_OFF);
    float* feats = (float*)(ws + FEATS_OFF);
    float* proj  = (float*)(ws + PROJ_OFF);
    float* w_wT  = (float*)(ws + WWT_OFF);
    u16*   whh_p = (u16*)  (ws + WHHP_OFF);
    float* bsum  = (float*)(ws + BSUM_OFF);
    float* sw1T  = (float*)(ws + SW1T_OFF);
    float* vw1T  = (float*)(ws + VW1T_OFF);
    float* alpha = (float*)(ws + SC_ALPHA);
    float* hx_g  = (float*)(ws + SC_HX);
    unsigned int* ctr = (unsigned int*)(ws + SC_CTR);
    unsigned int* rdy = (unsigned int*)(ws + SC_RDY);
    float* hseq  = (float*)(ws + HSEQ_OFF);
    u16*   G     = (u16*)  (ws + G_OFF);

    cam_to_cl<<<(NIMG*96*160 + 255)/256, 256, 0, stream>>>(cam, camcl);
    prep_wbf<<<64, 256, 0, stream>>>(cw1, w1b, 24,  3,  8, 5, 28, 32);
    prep_wbf<<<64, 256, 0, stream>>>(cw2, w2b, 36, 24, 24, 5, 28, 48);
    prep_wbf<<<64, 256, 0, stream>>>(cw3, w3b, 48, 36, 40, 5, 28, 48);
    prep_wbf<<<64, 256, 0, stream>>>(cw4, w4b, 64, 48, 48, 3, 10, 64);
    prep_wbf<<<64, 256, 0, stream>>>(cw5, w5b, 64, 64, 64, 3,  9, 64);

    conv_mfma<   8,    32,   24,  24,   5,  28,   2, 2, 96, 160, 48, 80,  8, 40>
        <<<dim3(12, NIMG), 256, 0, stream>>>(camcl, w1b, cb1, a1);
    conv_mfma<  24,    48,   36,  40,   5,  28,   2, 2, 48,  80, 24, 40,  8, 20>
        <<<dim3(6, NIMG), 256, 0, stream>>>(a1, w2b, cb2, a2);
    conv_mfma<  40,    48,   48,  48,   5,  28,   2, 2, 24,  40, 12, 20, 12, 20>
        <<<dim3(1, NIMG), 256, 0, stream>>>(a2, w3b, cb3, a3);
    conv_mfma<  48,    64,   64,  64,   3,  10,   1, 1, 12,  20, 12, 20, 12, 20>
        <<<dim3(1, NIMG), 256, 0, stream>>>(a3, w4b, cb4, a4);
    conv_mfma<  64,    64,   64,  64,   3,   9,   1, 1, 12,  20, 12, 20, 12, 20>
        <<<dim3(1, NIMG), 256, 0, stream>>>(a4, w5b, cb5, a5);

    extract_feats<<<(NIMG*12*20*64 + 255)/256, 256, 0, stream>>>(a5, feats);
    proj_kernel<<<NIMG*LL/4, 256, 0, stream>>>(feats, pw, pb, proj);
    prep<<<1024, 256, 0, stream>>>(w_w, whh, bih, bhh, w_wT, whh_p, bsum);
    gcompute_mfma2<<<dim3(8, 240), 256, 0, stream>>>(feats, wih, G);

    // zero scan state: alpha(4KB) + hx both parity buffers(16KB) + ctr(512B) + rdy(128B)
    hipMemsetAsync(ws + SC_ALPHA, 0, 21120, stream);

    scan_pc<<<TBLK, 256, 0, stream>>>(G, whh_p, bsum, proj, w_wT, w_b, waw, wab,
                                      alpha, hx_g, ctr, rdy, hseq);

    prep2<<<256, 256, 0, stream>>>(sw1, vw1, sw1T, vw1T);

    mlp_kernel<<<360, 256, 0, stream>>>(hseq,
        sw1T, sb1, sw2, sb2, sw3, sb3, sw4, sb4,
        vw1T, vb1, vw2, vb2, vw3, vb3, vw4, vb4, (float*)d_out);
}